// Round 1
// baseline (467.346 us; speedup 1.0000x reference)
//
#include <hip/hip_runtime.h>
#include <math.h>

#define TPB 256

// ---------------- layer geometry ----------------
constexpr int DIMS_[5]  = {480, 240, 120, 60, 30};          // H == W per layer
constexpr int CHS_ [5]  = {64, 128, 256, 512, 512};
constexpr int CHB_ [5]  = {0, 64, 192, 448, 960};           // cumulative channel base
constexpr int TOTCH     = 1472;
constexpr int PROCB_[5] = {0, 230400, 288000, 302400, 306000};
constexpr int PROCTOT   = 306900;

// ---------------- ws layout (units: 4-byte words) ----------------
constexpr int O_CHMIN = 0;            // f32 [1472]  (bit-pattern atomics)
constexpr int O_CHMAX = 1472;         // f32 [1472]
constexpr int O_HIST  = 2944;         // u32 [1472*6]
constexpr int O_GCNT  = 11776;        // u32 [1472*6]
constexpr int O_LUT2  = 20608;        // f32 [1472*6]
constexpr int O_BSUM  = 29440;        // f32 [5] per-layer border constant
constexpr int O_PMIN  = 29445;        // u32 [5]
constexpr int O_PMAX  = 29450;        // u32 [5]
constexpr int O_S3MIN = 29455;        // u32 [5]
constexpr int O_S3MAX = 29460;        // u32 [5]
constexpr int O_S3SUM = 29465;        // f32 [5]
constexpr int O_PROC  = 29472;        // f32 [306900]
constexpr int O_RESZ  = O_PROC + PROCTOT; // f32 [5*57600] — no init needed

struct P {
  const float* in[5];
  float* ws;
};

// ---------------- numerics helpers (must match numpy f32 op order) ----------------
__device__ __forceinline__ float normv(float v, float mn, float rng) {
#pragma clang fp contract(off)
  if (rng == 0.0f) return 0.0f;           // reference: rng==0 -> zeros
  return (v - mn) / rng * 256.0f;         // (x-mn)/safe*(hi-lo)+0
}
__device__ __forceinline__ int gbin(float nv) {
#pragma clang fp contract(off)
  float g = truncf(nv * 6.0f - 1.0f);     // trunc(ch*BINS - 1.0)
  g = fminf(fmaxf(g, 0.0f), 5.0f);
  return (int)g;
}
__device__ __forceinline__ int hbin(float nv) {
#pragma clang fp contract(off)
  float h = floorf(nv / (256.0f / 6.0f)); // floor(ch / (256/BINS))
  h = fminf(fmaxf(h, 0.0f), 5.0f);
  return (int)h;
}

// ---------------- init: zero stats + proc, +inf for min slots ----------------
__global__ void k_init(float* ws) {
  int i = blockIdx.x * TPB + threadIdx.x;
  if (i >= O_RESZ) return;
  unsigned v = 0u;
  if (i < O_CHMAX) v = 0x7F800000u;                       // chmin = +inf
  else if (i >= O_PMIN  && i < O_PMAX)  v = 0x7F800000u;  // pmin  = +inf
  else if (i >= O_S3MIN && i < O_S3MAX) v = 0x7F800000u;  // s3min = +inf
  ((unsigned*)ws)[i] = v;
}

// ---------------- pass A: per-channel min/max of zero-bordered map ----------------
template <int L>
__device__ void bodyA(int local, const float* __restrict__ in, float* ws) {
  constexpr int D = DIMS_[L];
  constexpr int HW = D * D;
  constexpr int BPC = (HW + 4095) / 4096;
  int ch = local / BPC, chunk = local % BPC;
  const float* p = in + (size_t)ch * HW;
  int t = threadIdx.x;
  float mn = INFINITY, mx = 0.0f;   // values >= 0; map contains border zeros
  #pragma unroll
  for (int i = 0; i < 16; i++) {
    int idx = chunk * 4096 + i * TPB + t;
    if (idx < HW) {
      int y = idx / D, x = idx - y * D;
      float v = (y == 0 || y == D - 1 || x == 0 || x == D - 1) ? 0.0f : p[idx];
      mn = fminf(mn, v); mx = fmaxf(mx, v);
    }
  }
  for (int o = 32; o; o >>= 1) { mn = fminf(mn, __shfl_down(mn, o)); mx = fmaxf(mx, __shfl_down(mx, o)); }
  __shared__ float smn[4], smx[4];
  int w = t >> 6;
  if ((t & 63) == 0) { smn[w] = mn; smx[w] = mx; }
  __syncthreads();
  if (t == 0) {
    mn = fminf(fminf(smn[0], smn[1]), fminf(smn[2], smn[3]));
    mx = fmaxf(fmaxf(smx[0], smx[1]), fmaxf(smx[2], smx[3]));
    int g = CHB_[L] + ch;
    atomicMin((unsigned*)ws + O_CHMIN + g, __float_as_uint(mn));
    atomicMax((unsigned*)ws + O_CHMAX + g, __float_as_uint(mx));
  }
}
__global__ void kA(P p) {
  int b = blockIdx.x;
  if      (b < 3648) bodyA<0>(b,        p.in[0], p.ws);
  else if (b < 5568) bodyA<1>(b - 3648, p.in[1], p.ws);
  else if (b < 6592) bodyA<2>(b - 5568, p.in[2], p.ws);
  else if (b < 7104) bodyA<3>(b - 6592, p.in[3], p.ws);
  else               bodyA<4>(b - 7104, p.in[4], p.ws);
}

// ---------------- pass B: per-channel hist (6) + gidx counts (6) ----------------
template <int L>
__device__ void bodyB(int local, const float* __restrict__ in, float* ws) {
  constexpr int D = DIMS_[L];
  constexpr int HW = D * D;
  constexpr int BPC = (HW + 4095) / 4096;
  int ch = local / BPC, chunk = local % BPC;
  int g = CHB_[L] + ch;
  float mn = ws[O_CHMIN + g], mx = ws[O_CHMAX + g];
  float rng = mx - mn;
  const float* p = in + (size_t)ch * HW;
  int t = threadIdx.x;
  unsigned hc[6] = {0, 0, 0, 0, 0, 0}, gc[6] = {0, 0, 0, 0, 0, 0};
  for (int i = 0; i < 16; i++) {
    int idx = chunk * 4096 + i * TPB + t;
    if (idx < HW) {
      int y = idx / D, x = idx - y * D;
      float v = (y == 0 || y == D - 1 || x == 0 || x == D - 1) ? 0.0f : p[idx];
      float nv = normv(v, mn, rng);
      int hb = hbin(nv), gb = gbin(nv);
      #pragma unroll
      for (int k = 0; k < 6; k++) { hc[k] += (hb == k); gc[k] += (gb == k); }
    }
  }
  #pragma unroll
  for (int k = 0; k < 6; k++)
    for (int o = 32; o; o >>= 1) { hc[k] += __shfl_down(hc[k], o); gc[k] += __shfl_down(gc[k], o); }
  if ((t & 63) == 0) {
    unsigned* H = (unsigned*)ws + O_HIST + g * 6;
    unsigned* G = (unsigned*)ws + O_GCNT + g * 6;
    #pragma unroll
    for (int k = 0; k < 6; k++) {
      if (hc[k]) atomicAdd(H + k, hc[k]);
      if (gc[k]) atomicAdd(G + k, gc[k]);
    }
  }
}
__global__ void kB(P p) {
  int b = blockIdx.x;
  if      (b < 3648) bodyB<0>(b,        p.in[0], p.ws);
  else if (b < 5568) bodyB<1>(b - 3648, p.in[1], p.ws);
  else if (b < 6592) bodyB<2>(b - 5568, p.in[2], p.ws);
  else if (b < 7104) bodyB<3>(b - 6592, p.in[3], p.ws);
  else               bodyB<4>(b - 7104, p.in[4], p.ws);
}

// ---------------- kernel S: per-channel LUT construction ----------------
__global__ void kS(P p) {
  int ch = blockIdx.x * TPB + threadIdx.x;
  if (ch >= TOTCH) return;
  float* ws = p.ws;
  int l = (ch < 64) ? 0 : (ch < 192) ? 1 : (ch < 448) ? 2 : (ch < 960) ? 3 : 4;
  int D = DIMS_[l];
  int HW = D * D;
  int c0 = ch - CHB_[l];
  unsigned hc[6], gc[6];
  unsigned* H = (unsigned*)ws + O_HIST + ch * 6;
  unsigned* G = (unsigned*)ws + O_GCNT + ch * 6;
  #pragma unroll
  for (int k = 0; k < 6; k++) { hc[k] = H[k]; gc[k] = G[k]; }
  float HWf = (float)HW;
  // stage 1: nh = -log(h/HW + 1e-4); dst normalize over occupied gidx values
  float nh[6];
  #pragma unroll
  for (int k = 0; k < 6; k++) nh[k] = -logf((float)hc[k] / HWf + 1e-4f);
  float dmn = INFINITY, dmx = -INFINITY;
  #pragma unroll
  for (int k = 0; k < 6; k++) if (gc[k]) { dmn = fminf(dmn, nh[k]); dmx = fmaxf(dmx, nh[k]); }
  float dr = dmx - dmn;
  float dstn[6];
  #pragma unroll
  for (int k = 0; k < 6; k++) dstn[k] = (dr == 0.0f) ? 0.0f : ((nh[k] - dmn) / dr);
  float maxv = (dr == 0.0f) ? 0.0f : 1.0f;  // max over map of normalized dst
  double s1 = 0.0;
  #pragma unroll
  for (int k = 0; k < 6; k++) s1 += (double)gc[k] * (double)dstn[k];
  float mean1 = (float)(s1 / (double)HW);
  float w1 = maxv - mean1; w1 *= w1;
  float lut1[6];
  #pragma unroll
  for (int k = 0; k < 6; k++) lut1[k] = dstn[k] * w1;   // r-map LUT (normalize is identity)
  // stage 2: ponder(maps[c]); c==0 keeps border (value lut1[gb]), c>=1 border zeroed
  float mnc = ws[O_CHMIN + ch], mxc = ws[O_CHMAX + ch];
  float rngc = mxc - mnc;
  int gb = gbin(normv(0.0f, mnc, rngc));   // gidx of border pixels (input value 0)
  unsigned bcnt = (unsigned)(4 * D - 4);
  float lmn, lmx;
  double s2 = 0.0;
  if (c0 == 0) {
    lmn = INFINITY; lmx = -INFINITY;
    #pragma unroll
    for (int k = 0; k < 6; k++) if (gc[k]) {
      lmn = fminf(lmn, lut1[k]); lmx = fmaxf(lmx, lut1[k]);
      s2 += (double)gc[k] * (double)lut1[k];
    }
  } else {
    lmn = 0.0f; lmx = 0.0f;   // border zeros present
    #pragma unroll
    for (int k = 0; k < 6; k++) {
      unsigned ic = gc[k] - ((k == gb) ? bcnt : 0u);
      if (ic) {
        lmn = fminf(lmn, lut1[k]); lmx = fmaxf(lmx, lut1[k]);
        s2 += (double)ic * (double)lut1[k];
      }
    }
  }
  float mean2 = (float)(s2 / (double)HW);
  float w2 = lmx - mean2; w2 *= w2;
  float r2 = lmx - lmn;
  float lout[6];
  #pragma unroll
  for (int k = 0; k < 6; k++) lout[k] = (r2 == 0.0f) ? 0.0f : (((lut1[k] - lmn) / r2) * w2);
  float* LT = ws + O_LUT2 + ch * 6;
  #pragma unroll
  for (int k = 0; k < 6; k++) LT[k] = lout[k];
  float bc = (c0 == 0) ? lout[gb] : ((r2 == 0.0f) ? 0.0f : (((0.0f - lmn) / r2) * w2));
  atomicAdd(ws + O_BSUM + l, bc);
}

// ---------------- pass C: proc = sum_c LUT2_c[gidx_c(pixel)] ----------------
template <int L>
__device__ void bodyC(int local, const float* __restrict__ in, float* ws) {
  constexpr int D = DIMS_[L];
  constexpr int HW = D * D;
  constexpr int C = CHS_[L];
  constexpr int PXB = (HW + 255) / 256;
  int pxc = local % PXB, cc = local / PXB;
  int c0 = cc * 128;
  int nch = (C - c0 < 128) ? (C - c0) : 128;
  __shared__ float smn[128], srg[128], slut[128 * 6];
  for (int i = threadIdx.x; i < nch; i += TPB) {
    int g = CHB_[L] + c0 + i;
    float m = ws[O_CHMIN + g];
    smn[i] = m; srg[i] = ws[O_CHMAX + g] - m;
  }
  for (int i = threadIdx.x; i < nch * 6; i += TPB)
    slut[i] = ws[O_LUT2 + (CHB_[L] + c0) * 6 + i];
  __syncthreads();
  int px = pxc * TPB + threadIdx.x;
  if (px >= HW) return;
  int y = px / D, x = px - y * D;
  float* procL = ws + O_PROC + PROCB_[L];
  if (y == 0 || y == D - 1 || x == 0 || x == D - 1) {
    if (cc == 0) procL[px] = ws[O_BSUM + L];   // all channels' border contributions
    return;
  }
  const float* bp = in + (size_t)c0 * HW + px;
  float s = 0.0f;
  for (int c = 0; c < nch; c++) {
    float v = bp[(size_t)c * HW];
    float nv = normv(v, smn[c], srg[c]);
    s += slut[c * 6 + gbin(nv)];
  }
  atomicAdd(procL + px, s);
}
__global__ void kC(P p) {
  int b = blockIdx.x;
  if      (b <  900) bodyC<0>(b,        p.in[0], p.ws);
  else if (b < 1125) bodyC<1>(b -  900, p.in[1], p.ws);
  else if (b < 1239) bodyC<2>(b - 1125, p.in[2], p.ws);
  else if (b < 1299) bodyC<3>(b - 1239, p.in[3], p.ws);
  else               bodyC<4>(b - 1299, p.in[4], p.ws);
}

// ---------------- pass D: per-layer proc min/max ----------------
template <int L>
__device__ void bodyD(int chunk, float* ws) {
  constexpr int HW = DIMS_[L] * DIMS_[L];
  const float* pr = ws + O_PROC + PROCB_[L];
  int t = threadIdx.x;
  float mn = INFINITY, mx = 0.0f;   // proc >= 0
  #pragma unroll
  for (int i = 0; i < 16; i++) {
    int idx = chunk * 4096 + i * TPB + t;
    if (idx < HW) { float v = pr[idx]; mn = fminf(mn, v); mx = fmaxf(mx, v); }
  }
  for (int o = 32; o; o >>= 1) { mn = fminf(mn, __shfl_down(mn, o)); mx = fmaxf(mx, __shfl_down(mx, o)); }
  __shared__ float smn[4], smx[4];
  int w = t >> 6;
  if ((t & 63) == 0) { smn[w] = mn; smx[w] = mx; }
  __syncthreads();
  if (t == 0) {
    mn = fminf(fminf(smn[0], smn[1]), fminf(smn[2], smn[3]));
    mx = fmaxf(fmaxf(smx[0], smx[1]), fmaxf(smx[2], smx[3]));
    atomicMin((unsigned*)ws + O_PMIN + L, __float_as_uint(mn));
    atomicMax((unsigned*)ws + O_PMAX + L, __float_as_uint(mx));
  }
}
__global__ void kD(P p) {
  int b = blockIdx.x;
  if      (b < 57) bodyD<0>(b,      p.ws);
  else if (b < 72) bodyD<1>(b - 57, p.ws);
  else if (b < 76) bodyD<2>(b - 72, p.ws);
  else if (b < 77) bodyD<3>(b - 76, p.ws);
  else             bodyD<4>(b - 77, p.ws);
}

// ---- pass F: fused normalize(proc,0,1) + threshold + jax.image.resize (triangle, antialias) ----
template <int L>
__device__ void bodyF(int px, float* ws) {
  constexpr int D = DIMS_[L];
  constexpr float INV = (float)D / 240.0f;           // inv_scale: 2,1,.5,.25,.125 (exact)
  constexpr float KS = (INV > 1.0f) ? INV : 1.0f;    // antialias kernel_scale
  int oy = px / 240, ox = px - oy * 240;
  float mnv = __uint_as_float(((unsigned*)ws)[O_PMIN + L]);
  float mxv = __uint_as_float(((unsigned*)ws)[O_PMAX + L]);
  float pr = mxv - mnv;
  const float* procL = ws + O_PROC + PROCB_[L];
  float sfy = ((float)oy + 0.5f) * INV - 0.5f;
  float sfx = ((float)ox + 0.5f) * INV - 0.5f;
  int y0 = (int)ceilf(sfy - KS);  if (y0 < 0) y0 = 0;
  int y1 = (int)floorf(sfy + KS); if (y1 > D - 1) y1 = D - 1;
  int x0 = (int)ceilf(sfx - KS);  if (x0 < 0) x0 = 0;
  int x1 = (int)floorf(sfx + KS); if (x1 > D - 1) x1 = D - 1;
  float wsx = 0.0f;
  for (int jx = x0; jx <= x1; jx++) wsx += fmaxf(1.0f - fabsf(sfx - (float)jx) / KS, 0.0f);
  float acc = 0.0f, wsy = 0.0f;
  for (int jy = y0; jy <= y1; jy++) {
    float wy = fmaxf(1.0f - fabsf(sfy - (float)jy) / KS, 0.0f);
    wsy += wy;
    if (wy > 0.0f) {
      const float* row = procL + jy * D;
      float rs = 0.0f;
      for (int jx = x0; jx <= x1; jx++) {
        float wx = fmaxf(1.0f - fabsf(sfx - (float)jx) / KS, 0.0f);
        if (wx > 0.0f) {
          float v = row[jx];
          float tv = (pr == 0.0f) ? 0.0f : ((v - mnv) / pr);  // normalize(proc,0,1)
          tv = (tv < 0.2f) ? 0.0f : tv;                       // threshold
          rs += wx * tv;
        }
      }
      acc += wy * rs;
    }
  }
  ws[O_RESZ + L * 57600 + px] = acc / (wsy * wsx);
}
__global__ void kF(P p) {
  int b = blockIdx.x;
  int l = b / 225;
  int px = (b - l * 225) * TPB + threadIdx.x;
  switch (l) {
    case 0: bodyF<0>(px, p.ws); break;
    case 1: bodyF<1>(px, p.ws); break;
    case 2: bodyF<2>(px, p.ws); break;
    case 3: bodyF<3>(px, p.ws); break;
    default: bodyF<4>(px, p.ws); break;
  }
}

// ---------------- G1: per-layer resized min/max/sum ----------------
__global__ void kG1(P p) {
  float* ws = p.ws;
  int b = blockIdx.x, l = b / 225;
  int px = (b - l * 225) * TPB + threadIdx.x;
  float v = ws[O_RESZ + l * 57600 + px];
  float mn = v, mx = v, s = v;
  for (int o = 32; o; o >>= 1) {
    mn = fminf(mn, __shfl_down(mn, o));
    mx = fmaxf(mx, __shfl_down(mx, o));
    s += __shfl_down(s, o);
  }
  __shared__ float smn[4], smx[4], ssm[4];
  int t = threadIdx.x, w = t >> 6;
  if ((t & 63) == 0) { smn[w] = mn; smx[w] = mx; ssm[w] = s; }
  __syncthreads();
  if (t == 0) {
    mn = fminf(fminf(smn[0], smn[1]), fminf(smn[2], smn[3]));
    mx = fmaxf(fmaxf(smx[0], smx[1]), fmaxf(smx[2], smx[3]));
    s = ssm[0] + ssm[1] + ssm[2] + ssm[3];
    atomicMin((unsigned*)ws + O_S3MIN + l, __float_as_uint(mn));
    atomicMax((unsigned*)ws + O_S3MAX + l, __float_as_uint(mx));
    atomicAdd(ws + O_S3SUM + l, s);
  }
}

// ---------------- G2: final ponder + normalize(.,0,256), groups + sum ----------------
__global__ void kG2(P p, float* __restrict__ out) {
  float* ws = p.ws;
  int px = blockIdx.x * TPB + threadIdx.x;   // 225*256 == 57600 exactly
  float sum = 0.0f;
  #pragma unroll
  for (int l = 0; l < 5; l++) {
    float v = ws[O_RESZ + l * 57600 + px];
    float mn3 = __uint_as_float(((unsigned*)ws)[O_S3MIN + l]);
    float mx3 = __uint_as_float(((unsigned*)ws)[O_S3MAX + l]);
    float mean3 = ws[O_S3SUM + l] / 57600.0f;
    float r3 = mx3 - mn3;
    float ov;
    if (r3 == 0.0f) ov = 0.0f;
    else {
      float w3 = mx3 - mean3; w3 *= w3;
      if (w3 == 0.0f) ov = 0.0f;
      else {
        float pn = ((v - mn3) / r3) * w3;  // _ponder: normalize(x)*w
        ov = pn / w3 * 256.0f;             // normalize(pn, 0, 256): min=0, max=w3
      }
    }
    out[57600 + px * 5 + l] = ov;
    sum += ov;
  }
  out[px] = sum;
}

extern "C" void kernel_launch(void* const* d_in, const int* in_sizes, int n_in,
                              void* d_out, int out_size, void* d_ws, size_t ws_size,
                              hipStream_t stream) {
  (void)in_sizes; (void)n_in; (void)out_size; (void)ws_size;
  P p;
  for (int i = 0; i < 5; i++) p.in[i] = (const float*)d_in[i];
  p.ws = (float*)d_ws;
  float* out = (float*)d_out;

  k_init<<<(O_RESZ + TPB - 1) / TPB, TPB, 0, stream>>>(p.ws);
  kA  <<<7616, TPB, 0, stream>>>(p);
  kB  <<<7616, TPB, 0, stream>>>(p);
  kS  <<<6,    TPB, 0, stream>>>(p);
  kC  <<<1315, TPB, 0, stream>>>(p);
  kD  <<<78,   TPB, 0, stream>>>(p);
  kF  <<<1125, TPB, 0, stream>>>(p);
  kG1 <<<1125, TPB, 0, stream>>>(p);
  kG2 <<<225,  TPB, 0, stream>>>(p, out);
}

// Round 2
// 415.337 us; speedup vs baseline: 1.1252x; 1.1252x over previous
//
#include <hip/hip_runtime.h>
#include <math.h>

#define TPB 256

// ---------------- layer geometry ----------------
constexpr int DIMS_[5]  = {480, 240, 120, 60, 30};
constexpr int CHS_ [5]  = {64, 128, 256, 512, 512};
constexpr int CHB_ [5]  = {0, 64, 192, 448, 960};
constexpr int TOTCH     = 1472;
constexpr int PROCB_[5] = {0, 230400, 288000, 302400, 306000};
constexpr int PROCTOT   = 306900;

// ---------------- ws layout (4-byte words) ----------------
constexpr int O_CHMIN = 0;                  // f32 [1472]
constexpr int O_CHMAX = 1472;               // f32 [1472]
constexpr int O_HIST  = 2944;               // u32 [1472*6]
constexpr int O_GCNT  = 11776;              // u32 [1472*6]
constexpr int O_CLUT  = 20608;              // f32 [1472*16]: hthr[5], gthr[5], lut[6]
constexpr int O_BSUM  = O_CLUT + 16 * 1472; // 44160: f32 [5]
constexpr int O_PMIN  = O_BSUM + 5;         // u32 [5]
constexpr int O_PMAX  = O_PMIN + 5;         // u32 [5]
constexpr int O_S3MIN = O_PMAX + 5;         // u32 [5]
constexpr int O_S3MAX = O_S3MIN + 5;        // u32 [5]
constexpr int O_S3SUM = O_S3MAX + 5;        // f32 [5]
constexpr int O_PROC  = 44192;              // f32 [306900]
constexpr int O_RESZ  = O_PROC + PROCTOT;   // f32 [5*57600]

struct P {
  const float* in[5];
  float* ws;
};

// ---------------- init: stats region only (proc/resz written directly) ----------------
__global__ void k_init(float* ws) {
  int i = blockIdx.x * TPB + threadIdx.x;
  if (i >= O_PROC) return;
  unsigned v = 0u;
  if (i < O_CHMAX) v = 0x7F800000u;                       // chmin = +inf
  else if (i >= O_PMIN  && i < O_PMAX)  v = 0x7F800000u;  // pmin
  else if (i >= O_S3MIN && i < O_S3MAX) v = 0x7F800000u;  // s3min
  ((unsigned*)ws)[i] = v;
}

// ---------------- pass A: per-channel min/max of border-zeroed map (float4) ----------------
template <int L>
__device__ void bodyA(int local, const float* __restrict__ in, float* ws) {
  constexpr int D = DIMS_[L], HW = D * D, HW4 = HW / 4;
  constexpr int BPC = (HW4 + 4095) / 4096;
  int ch = local / BPC, chunk = local % BPC;
  int nvec = HW4 - chunk * 4096; if (nvec > 4096) nvec = 4096;
  const float4* pv = (const float4*)(in + (size_t)ch * HW) + (size_t)chunk * 4096;
  int t = threadIdx.x;
  float mn = INFINITY, mx = 0.0f;
  for (int i = 0; i < 16; i++) {
    int vi = i * TPB + t;
    if (vi < nvec) {
      float4 v = pv[vi];
      float vv[4] = {v.x, v.y, v.z, v.w};
      int e0 = (chunk * 4096 + vi) * 4;
      #pragma unroll
      for (int j = 0; j < 4; j++) {
        int e = e0 + j, y = e / D, x = e - y * D;
        bool inr = ((unsigned)(x - 1) < (unsigned)(D - 2)) && ((unsigned)(y - 1) < (unsigned)(D - 2));
        float s = inr ? vv[j] : 0.0f;   // border-as-zero: exact map semantics
        mn = fminf(mn, s); mx = fmaxf(mx, s);
      }
    }
  }
  for (int o = 32; o; o >>= 1) { mn = fminf(mn, __shfl_down(mn, o)); mx = fmaxf(mx, __shfl_down(mx, o)); }
  __shared__ float smn[4], smx[4];
  int w = t >> 6;
  if ((t & 63) == 0) { smn[w] = mn; smx[w] = mx; }
  __syncthreads();
  if (t == 0) {
    mn = fminf(fminf(smn[0], smn[1]), fminf(smn[2], smn[3]));
    mx = fmaxf(fmaxf(smx[0], smx[1]), fmaxf(smx[2], smx[3]));
    int g = CHB_[L] + ch;
    atomicMin((unsigned*)ws + O_CHMIN + g, __float_as_uint(mn));  // values >= 0
    atomicMax((unsigned*)ws + O_CHMAX + g, __float_as_uint(mx));
  }
}
__global__ void kA(P p) {
  int b = blockIdx.x;
  if      (b <  960) bodyA<0>(b,        p.in[0], p.ws);
  else if (b < 1472) bodyA<1>(b -  960, p.in[1], p.ws);
  else if (b < 1728) bodyA<2>(b - 1472, p.in[2], p.ws);
  else if (b < 2240) bodyA<3>(b - 1728, p.in[3], p.ws);
  else               bodyA<4>(b - 2240, p.in[4], p.ws);
}

// ---- kTB: per-channel thresholds + border fixup (subtract actual bins, add border-as-zero) ----
__global__ void kTB(P p) {
  int ch = blockIdx.x;
  float* ws = p.ws;
  int l = (ch < 64) ? 0 : (ch < 192) ? 1 : (ch < 448) ? 2 : (ch < 960) ? 3 : 4;
  int D = DIMS_[l];
  float mn = ws[O_CHMIN + ch], mx = ws[O_CHMAX + ch];
  float rng = mx - mn;
  // hb >= k  <=>  v >= mn + rng*k/6          (k = 1..5)
  // gb >= k  <=>  v >= mn + rng*(k+1)/1536   (k = 1..5)
  float th0, th1, th2, th3, th4, tg0, tg1, tg2, tg3, tg4;
  if (rng == 0.0f) {
    th0 = th1 = th2 = th3 = th4 = tg0 = tg1 = tg2 = tg3 = tg4 = INFINITY;
  } else {
    th0 = mn + rng * (1.0f / 6.0f); th1 = mn + rng * (2.0f / 6.0f);
    th2 = mn + rng * (3.0f / 6.0f); th3 = mn + rng * (4.0f / 6.0f);
    th4 = mn + rng * (5.0f / 6.0f);
    tg0 = mn + rng * (2.0f / 1536.0f); tg1 = mn + rng * (3.0f / 1536.0f);
    tg2 = mn + rng * (4.0f / 1536.0f); tg3 = mn + rng * (5.0f / 1536.0f);
    tg4 = mn + rng * (6.0f / 1536.0f);
  }
  int t = threadIdx.x;
  if (t == 0) {
    float* T = ws + O_CLUT + (size_t)ch * 16;
    T[0] = th0; T[1] = th1; T[2] = th2; T[3] = th3; T[4] = th4;
    T[5] = tg0; T[6] = tg1; T[7] = tg2; T[8] = tg3; T[9] = tg4;
  }
  // border pixels: count actual-value bins (to subtract from kB's full counts)
  const float* in = p.in[l] + (size_t)(ch - CHB_[l]) * D * D;
  int nb = 4 * D - 4;
  unsigned cH0 = 0, cH1 = 0, cH2 = 0, cH3 = 0, cH4 = 0;
  unsigned cG0 = 0, cG1 = 0, cG2 = 0, cG3 = 0, cG4 = 0, nval = 0;
  for (int j = t; j < nb; j += TPB) {
    int y, x;
    if (j < D)            { y = 0;               x = j;          }
    else if (j < 2 * D)   { y = D - 1;           x = j - D;      }
    else if (j < 3 * D - 2){ y = j - 2 * D + 1;  x = 0;          }
    else                  { y = j - (3 * D - 2) + 1; x = D - 1;  }
    float v = in[y * D + x];
    nval += __popcll(__ballot(1));
    cH0 += __popcll(__ballot(v >= th0)); cH1 += __popcll(__ballot(v >= th1));
    cH2 += __popcll(__ballot(v >= th2)); cH3 += __popcll(__ballot(v >= th3));
    cH4 += __popcll(__ballot(v >= th4));
    cG0 += __popcll(__ballot(v >= tg0)); cG1 += __popcll(__ballot(v >= tg1));
    cG2 += __popcll(__ballot(v >= tg2)); cG3 += __popcll(__ballot(v >= tg3));
    cG4 += __popcll(__ballot(v >= tg4));
  }
  unsigned* H = (unsigned*)ws + O_HIST + ch * 6;
  unsigned* G = (unsigned*)ws + O_GCNT + ch * 6;
  if ((t & 63) == 0) {
    atomicAdd(H + 0, (unsigned)(-(int)(nval - cH0)));
    atomicAdd(H + 1, (unsigned)(-(int)(cH0 - cH1)));
    atomicAdd(H + 2, (unsigned)(-(int)(cH1 - cH2)));
    atomicAdd(H + 3, (unsigned)(-(int)(cH2 - cH3)));
    atomicAdd(H + 4, (unsigned)(-(int)(cH3 - cH4)));
    atomicAdd(H + 5, (unsigned)(-(int)cH4));
    atomicAdd(G + 0, (unsigned)(-(int)(nval - cG0)));
    atomicAdd(G + 1, (unsigned)(-(int)(cG0 - cG1)));
    atomicAdd(G + 2, (unsigned)(-(int)(cG1 - cG2)));
    atomicAdd(G + 3, (unsigned)(-(int)(cG2 - cG3)));
    atomicAdd(G + 4, (unsigned)(-(int)(cG3 - cG4)));
    atomicAdd(G + 5, (unsigned)(-(int)cG4));
  }
  if (t == 0) {   // border-as-zero analytic counts
    int hb0 = (0.0f >= th0) + (0.0f >= th1) + (0.0f >= th2) + (0.0f >= th3) + (0.0f >= th4);
    int gb0 = (0.0f >= tg0) + (0.0f >= tg1) + (0.0f >= tg2) + (0.0f >= tg3) + (0.0f >= tg4);
    atomicAdd(H + hb0, (unsigned)nb);
    atomicAdd(G + gb0, (unsigned)nb);
  }
}

// ---------------- pass B: hist + gidx counts via ballots (no border logic) ----------------
template <int L>
__device__ void bodyB(int local, const float* __restrict__ in, float* ws) {
  constexpr int D = DIMS_[L], HW = D * D, HW4 = HW / 4;
  constexpr int BPC = (HW4 + 4095) / 4096;
  int ch = local / BPC, chunk = local % BPC;
  int g = CHB_[L] + ch;
  const float* T = ws + O_CLUT + (size_t)g * 16;
  float th0 = T[0], th1 = T[1], th2 = T[2], th3 = T[3], th4 = T[4];
  float tg0 = T[5], tg1 = T[6], tg2 = T[7], tg3 = T[8], tg4 = T[9];
  int nvec = HW4 - chunk * 4096; if (nvec > 4096) nvec = 4096;
  const float4* pv = (const float4*)(in + (size_t)ch * HW) + (size_t)chunk * 4096;
  int t = threadIdx.x;
  unsigned cH0 = 0, cH1 = 0, cH2 = 0, cH3 = 0, cH4 = 0;
  unsigned cG0 = 0, cG1 = 0, cG2 = 0, cG3 = 0, cG4 = 0, nv4 = 0;
  for (int i = 0; i < 16; i++) {
    int vi = i * TPB + t;
    if (vi < nvec) {
      float4 v = pv[vi];
      nv4 += __popcll(__ballot(1));
      float vv[4] = {v.x, v.y, v.z, v.w};
      #pragma unroll
      for (int j = 0; j < 4; j++) {
        float x = vv[j];
        cH0 += __popcll(__ballot(x >= th0)); cH1 += __popcll(__ballot(x >= th1));
        cH2 += __popcll(__ballot(x >= th2)); cH3 += __popcll(__ballot(x >= th3));
        cH4 += __popcll(__ballot(x >= th4));
        cG0 += __popcll(__ballot(x >= tg0)); cG1 += __popcll(__ballot(x >= tg1));
        cG2 += __popcll(__ballot(x >= tg2)); cG3 += __popcll(__ballot(x >= tg3));
        cG4 += __popcll(__ballot(x >= tg4));
      }
    }
  }
  if ((t & 63) == 0) {
    unsigned tot = nv4 * 4u;
    unsigned* H = (unsigned*)ws + O_HIST + g * 6;
    unsigned* G = (unsigned*)ws + O_GCNT + g * 6;
    atomicAdd(H + 0, tot - cH0); atomicAdd(H + 1, cH0 - cH1);
    atomicAdd(H + 2, cH1 - cH2); atomicAdd(H + 3, cH2 - cH3);
    atomicAdd(H + 4, cH3 - cH4); atomicAdd(H + 5, cH4);
    atomicAdd(G + 0, tot - cG0); atomicAdd(G + 1, cG0 - cG1);
    atomicAdd(G + 2, cG1 - cG2); atomicAdd(G + 3, cG2 - cG3);
    atomicAdd(G + 4, cG3 - cG4); atomicAdd(G + 5, cG4);
  }
}
__global__ void kB(P p) {
  int b = blockIdx.x;
  if      (b <  960) bodyB<0>(b,        p.in[0], p.ws);
  else if (b < 1472) bodyB<1>(b -  960, p.in[1], p.ws);
  else if (b < 1728) bodyB<2>(b - 1472, p.in[2], p.ws);
  else if (b < 2240) bodyB<3>(b - 1728, p.in[3], p.ws);
  else               bodyB<4>(b - 2240, p.in[4], p.ws);
}

// ---------------- kernel S: per-channel LUT construction ----------------
__global__ void kS(P p) {
  int ch = blockIdx.x * TPB + threadIdx.x;
  if (ch >= TOTCH) return;
  float* ws = p.ws;
  int l = (ch < 64) ? 0 : (ch < 192) ? 1 : (ch < 448) ? 2 : (ch < 960) ? 3 : 4;
  int D = DIMS_[l];
  int HW = D * D;
  int c0 = ch - CHB_[l];
  unsigned hc[6], gc[6];
  unsigned* H = (unsigned*)ws + O_HIST + ch * 6;
  unsigned* G = (unsigned*)ws + O_GCNT + ch * 6;
  #pragma unroll
  for (int k = 0; k < 6; k++) { hc[k] = H[k]; gc[k] = G[k]; }
  float HWf = (float)HW;
  float nh[6];
  #pragma unroll
  for (int k = 0; k < 6; k++) nh[k] = -logf((float)hc[k] / HWf + 1e-4f);
  float dmn = INFINITY, dmx = -INFINITY;
  #pragma unroll
  for (int k = 0; k < 6; k++) if (gc[k]) { dmn = fminf(dmn, nh[k]); dmx = fmaxf(dmx, nh[k]); }
  float dr = dmx - dmn;
  float dstn[6];
  #pragma unroll
  for (int k = 0; k < 6; k++) dstn[k] = (dr == 0.0f) ? 0.0f : ((nh[k] - dmn) / dr);
  float maxv = (dr == 0.0f) ? 0.0f : 1.0f;
  double s1 = 0.0;
  #pragma unroll
  for (int k = 0; k < 6; k++) s1 += (double)gc[k] * (double)dstn[k];
  float mean1 = (float)(s1 / (double)HW);
  float w1 = maxv - mean1; w1 *= w1;
  float lut1[6];
  #pragma unroll
  for (int k = 0; k < 6; k++) lut1[k] = dstn[k] * w1;
  // border-as-zero gidx bin (must match kTB)
  const float* T = ws + O_CLUT + (size_t)ch * 16;
  int gb = (0.0f >= T[5]) + (0.0f >= T[6]) + (0.0f >= T[7]) + (0.0f >= T[8]) + (0.0f >= T[9]);
  unsigned bcnt = (unsigned)(4 * D - 4);
  float lmn, lmx;
  double s2 = 0.0;
  if (c0 == 0) {   // channel 0 keeps its border
    lmn = INFINITY; lmx = -INFINITY;
    #pragma unroll
    for (int k = 0; k < 6; k++) if (gc[k]) {
      lmn = fminf(lmn, lut1[k]); lmx = fmaxf(lmx, lut1[k]);
      s2 += (double)gc[k] * (double)lut1[k];
    }
  } else {
    lmn = 0.0f; lmx = 0.0f;   // border zeros present
    #pragma unroll
    for (int k = 0; k < 6; k++) {
      unsigned ic = gc[k] - ((k == gb) ? bcnt : 0u);
      if (ic) {
        lmn = fminf(lmn, lut1[k]); lmx = fmaxf(lmx, lut1[k]);
        s2 += (double)ic * (double)lut1[k];
      }
    }
  }
  float mean2 = (float)(s2 / (double)HW);
  float w2 = lmx - mean2; w2 *= w2;
  float r2 = lmx - lmn;
  float lout[6];
  #pragma unroll
  for (int k = 0; k < 6; k++) lout[k] = (r2 == 0.0f) ? 0.0f : (((lut1[k] - lmn) / r2) * w2);
  float* LT = ws + O_CLUT + (size_t)ch * 16 + 10;
  #pragma unroll
  for (int k = 0; k < 6; k++) LT[k] = lout[k];
  float bc = (c0 == 0) ? lout[gb] : ((r2 == 0.0f) ? 0.0f : (((0.0f - lmn) / r2) * w2));
  atomicAdd(ws + O_BSUM + l, bc);
}

// ---- pass C: proc = sum_c LUT[gb_c(v)], 64 px x 4 channel-groups, fused layer min/max ----
template <int L>
__device__ void bodyC(int local, const float* __restrict__ in, float* ws, float* sred) {
  constexpr int D = DIMS_[L], HW = D * D, C = CHS_[L];
  int t = threadIdx.x, lane = t & 63, w = t >> 6;
  int px = local * 64 + lane;
  bool valid = px < HW;
  int y = px / D, x = px - y * D;
  bool inr = valid && ((unsigned)(x - 1) < (unsigned)(D - 2)) && ((unsigned)(y - 1) < (unsigned)(D - 2));
  float acc = 0.0f;
  if (inr) {
    const float* bp = in + px;
    #pragma unroll 4
    for (int c = w; c < C; c += 4) {
      const float* cl = ws + O_CLUT + (size_t)(CHB_[L] + c) * 16 + 5;  // gthr[5], lut[6]
      float g0 = cl[0], g1 = cl[1], g2 = cl[2], g3 = cl[3], g4 = cl[4];
      float l0 = cl[5], l1 = cl[6], l2 = cl[7], l3 = cl[8], l4 = cl[9], l5 = cl[10];
      float v = bp[(size_t)c * HW];
      float val = (v >= g0) ? l1 : l0;
      val = (v >= g1) ? l2 : val;
      val = (v >= g2) ? l3 : val;
      val = (v >= g3) ? l4 : val;
      val = (v >= g4) ? l5 : val;
      acc += val;
    }
  }
  sred[w * 64 + lane] = acc;
  __syncthreads();
  if (w == 0) {
    float outv = sred[lane] + sred[64 + lane] + sred[128 + lane] + sred[192 + lane];
    if (!inr) outv = ws[O_BSUM + L];   // border constant (invalid lanes masked below)
    float* procL = ws + O_PROC + PROCB_[L];
    if (valid) procL[px] = outv;
    float mnv = valid ? outv : INFINITY;
    float mxv = valid ? outv : 0.0f;
    for (int o = 32; o; o >>= 1) { mnv = fminf(mnv, __shfl_down(mnv, o)); mxv = fmaxf(mxv, __shfl_down(mxv, o)); }
    if (lane == 0) {
      atomicMin((unsigned*)ws + O_PMIN + L, __float_as_uint(mnv));
      atomicMax((unsigned*)ws + O_PMAX + L, __float_as_uint(mxv));
    }
  }
}
__global__ void kC(P p) {
  __shared__ float sred[256];
  int b = blockIdx.x;
  if      (b < 3600) bodyC<0>(b,        p.in[0], p.ws, sred);
  else if (b < 4500) bodyC<1>(b - 3600, p.in[1], p.ws, sred);
  else if (b < 4725) bodyC<2>(b - 4500, p.in[2], p.ws, sred);
  else if (b < 4782) bodyC<3>(b - 4725, p.in[3], p.ws, sred);
  else               bodyC<4>(b - 4782, p.in[4], p.ws, sred);
}

// ---- pass F: normalize(proc,0,1) + threshold + jax bilinear resize, fused layer stats ----
template <int L>
__device__ float bodyF(int px, float* ws) {
  constexpr int D = DIMS_[L];
  constexpr float INV = (float)D / 240.0f;
  constexpr float KS = (INV > 1.0f) ? INV : 1.0f;
  int oy = px / 240, ox = px - oy * 240;
  float mnv = __uint_as_float(((unsigned*)ws)[O_PMIN + L]);
  float mxv = __uint_as_float(((unsigned*)ws)[O_PMAX + L]);
  float pr = mxv - mnv;
  const float* procL = ws + O_PROC + PROCB_[L];
  float sfy = ((float)oy + 0.5f) * INV - 0.5f;
  float sfx = ((float)ox + 0.5f) * INV - 0.5f;
  int y0 = (int)ceilf(sfy - KS);  if (y0 < 0) y0 = 0;
  int y1 = (int)floorf(sfy + KS); if (y1 > D - 1) y1 = D - 1;
  int x0 = (int)ceilf(sfx - KS);  if (x0 < 0) x0 = 0;
  int x1 = (int)floorf(sfx + KS); if (x1 > D - 1) x1 = D - 1;
  float wsx = 0.0f;
  for (int jx = x0; jx <= x1; jx++) wsx += fmaxf(1.0f - fabsf(sfx - (float)jx) / KS, 0.0f);
  float acc = 0.0f, wsy = 0.0f;
  for (int jy = y0; jy <= y1; jy++) {
    float wy = fmaxf(1.0f - fabsf(sfy - (float)jy) / KS, 0.0f);
    wsy += wy;
    if (wy > 0.0f) {
      const float* row = procL + jy * D;
      float rs = 0.0f;
      for (int jx = x0; jx <= x1; jx++) {
        float wx = fmaxf(1.0f - fabsf(sfx - (float)jx) / KS, 0.0f);
        if (wx > 0.0f) {
          float v = row[jx];
          float tv = (pr == 0.0f) ? 0.0f : ((v - mnv) / pr);
          tv = (tv < 0.2f) ? 0.0f : tv;
          rs += wx * tv;
        }
      }
      acc += wy * rs;
    }
  }
  return acc / (wsy * wsx);
}
__global__ void kF(P p) {
  float* ws = p.ws;
  int b = blockIdx.x, l = b / 225;
  int px = (b - l * 225) * TPB + threadIdx.x;
  float res;
  switch (l) {
    case 0: res = bodyF<0>(px, ws); break;
    case 1: res = bodyF<1>(px, ws); break;
    case 2: res = bodyF<2>(px, ws); break;
    case 3: res = bodyF<3>(px, ws); break;
    default: res = bodyF<4>(px, ws); break;
  }
  ws[O_RESZ + l * 57600 + px] = res;
  float mn = res, mx = res, s = res;
  for (int o = 32; o; o >>= 1) {
    mn = fminf(mn, __shfl_down(mn, o));
    mx = fmaxf(mx, __shfl_down(mx, o));
    s += __shfl_down(s, o);
  }
  __shared__ float smn[4], smx[4], ssm[4];
  int t = threadIdx.x, w = t >> 6;
  if ((t & 63) == 0) { smn[w] = mn; smx[w] = mx; ssm[w] = s; }
  __syncthreads();
  if (t == 0) {
    mn = fminf(fminf(smn[0], smn[1]), fminf(smn[2], smn[3]));
    mx = fmaxf(fmaxf(smx[0], smx[1]), fmaxf(smx[2], smx[3]));
    s = ssm[0] + ssm[1] + ssm[2] + ssm[3];
    atomicMin((unsigned*)ws + O_S3MIN + l, __float_as_uint(mn));
    atomicMax((unsigned*)ws + O_S3MAX + l, __float_as_uint(mx));
    atomicAdd(ws + O_S3SUM + l, s);
  }
}

// ---------------- G2: final ponder + normalize(.,0,256), groups + sum ----------------
__global__ void kG2(P p, float* __restrict__ out) {
  float* ws = p.ws;
  int px = blockIdx.x * TPB + threadIdx.x;   // 225*256 == 57600
  float sum = 0.0f;
  #pragma unroll
  for (int l = 0; l < 5; l++) {
    float v = ws[O_RESZ + l * 57600 + px];
    float mn3 = __uint_as_float(((unsigned*)ws)[O_S3MIN + l]);
    float mx3 = __uint_as_float(((unsigned*)ws)[O_S3MAX + l]);
    float mean3 = ws[O_S3SUM + l] / 57600.0f;
    float r3 = mx3 - mn3;
    float ov;
    if (r3 == 0.0f) ov = 0.0f;
    else {
      float w3 = mx3 - mean3; w3 *= w3;
      if (w3 == 0.0f) ov = 0.0f;
      else ov = ((v - mn3) / r3) * w3 / w3 * 256.0f;
    }
    out[57600 + px * 5 + l] = ov;
    sum += ov;
  }
  out[px] = sum;
}

extern "C" void kernel_launch(void* const* d_in, const int* in_sizes, int n_in,
                              void* d_out, int out_size, void* d_ws, size_t ws_size,
                              hipStream_t stream) {
  (void)in_sizes; (void)n_in; (void)out_size; (void)ws_size;
  P p;
  for (int i = 0; i < 5; i++) p.in[i] = (const float*)d_in[i];
  p.ws = (float*)d_ws;
  float* out = (float*)d_out;

  k_init<<<(O_PROC + TPB - 1) / TPB, TPB, 0, stream>>>(p.ws);
  kA  <<<2752, TPB, 0, stream>>>(p);
  kTB <<<1472, TPB, 0, stream>>>(p);
  kB  <<<2752, TPB, 0, stream>>>(p);
  kS  <<<6,    TPB, 0, stream>>>(p);
  kC  <<<4797, TPB, 0, stream>>>(p);
  kF  <<<1125, TPB, 0, stream>>>(p);
  kG2 <<<225,  TPB, 0, stream>>>(p, out);
}

// Round 3
// 339.304 us; speedup vs baseline: 1.3774x; 1.2241x over previous
//
#include <hip/hip_runtime.h>
#include <math.h>

#define TPB 256

// ---------------- layer geometry ----------------
constexpr int DIMS_[5]  = {480, 240, 120, 60, 30};
constexpr int CHS_ [5]  = {64, 128, 256, 512, 512};
constexpr int CHB_ [5]  = {0, 64, 192, 448, 960};
constexpr int TOTCH     = 1472;
constexpr int PROCB_[5] = {0, 230400, 288000, 302400, 306000};
constexpr int PROCTOT   = 306900;

// ---------------- ws layout (4-byte words) ----------------
constexpr int O_CHMIN = 0;                  // f32 [1472]
constexpr int O_CHMAX = 1472;               // f32 [1472]
constexpr int O_HIST  = 2944;               // u32 [1472*6]
constexpr int O_GCNT  = 11776;              // u32 [1472*6]
constexpr int O_CLUT  = 20608;              // f32 [1472*16]: hthr[5], gthr[5], lut[6]
constexpr int O_BSUM  = O_CLUT + 16 * 1472; // 44160: f32 [5]
constexpr int O_PMIN  = O_BSUM + 5;         // u32 [5]
constexpr int O_PMAX  = O_PMIN + 5;         // u32 [5]
constexpr int O_S3MIN = O_PMAX + 5;         // u32 [5]
constexpr int O_S3MAX = O_S3MIN + 5;        // u32 [5]
constexpr int O_S3SUM = O_S3MAX + 5;        // f32 [5]
constexpr int O_PROC  = 44192;              // f32 [306900]
constexpr int O_RESZ  = O_PROC + PROCTOT;   // f32 [5*57600]

struct P {
  const float* in[5];
  float* ws;
};

// ---------------- init: stats region only (proc/resz written directly) ----------------
__global__ void k_init(float* ws) {
  int i = blockIdx.x * TPB + threadIdx.x;
  if (i >= O_PROC) return;
  unsigned v = 0u;
  if (i < O_CHMAX) v = 0x7F800000u;                       // chmin = +inf
  else if (i >= O_PMIN  && i < O_PMAX)  v = 0x7F800000u;  // pmin
  else if (i >= O_S3MIN && i < O_S3MAX) v = 0x7F800000u;  // s3min
  ((unsigned*)ws)[i] = v;
}

// ---------------- pass A: per-channel min/max of border-zeroed map (float4) ----------------
template <int L>
__device__ void bodyA(int local, const float* __restrict__ in, float* ws) {
  constexpr int D = DIMS_[L], HW = D * D, HW4 = HW / 4;
  constexpr int BPC = (HW4 + 4095) / 4096;
  int ch = local / BPC, chunk = local % BPC;
  int nvec = HW4 - chunk * 4096; if (nvec > 4096) nvec = 4096;
  const float4* pv = (const float4*)(in + (size_t)ch * HW) + (size_t)chunk * 4096;
  int t = threadIdx.x;
  float mn = INFINITY, mx = 0.0f;
  for (int i = 0; i < 16; i++) {
    int vi = i * TPB + t;
    if (vi < nvec) {
      float4 v = pv[vi];
      float vv[4] = {v.x, v.y, v.z, v.w};
      int e0 = (chunk * 4096 + vi) * 4;
      #pragma unroll
      for (int j = 0; j < 4; j++) {
        int e = e0 + j, y = e / D, x = e - y * D;
        bool inr = ((unsigned)(x - 1) < (unsigned)(D - 2)) && ((unsigned)(y - 1) < (unsigned)(D - 2));
        float s = inr ? vv[j] : 0.0f;   // border-as-zero: exact map semantics
        mn = fminf(mn, s); mx = fmaxf(mx, s);
      }
    }
  }
  for (int o = 32; o; o >>= 1) { mn = fminf(mn, __shfl_down(mn, o)); mx = fmaxf(mx, __shfl_down(mx, o)); }
  __shared__ float smn[4], smx[4];
  int w = t >> 6;
  if ((t & 63) == 0) { smn[w] = mn; smx[w] = mx; }
  __syncthreads();
  if (t == 0) {
    mn = fminf(fminf(smn[0], smn[1]), fminf(smn[2], smn[3]));
    mx = fmaxf(fmaxf(smx[0], smx[1]), fmaxf(smx[2], smx[3]));
    int g = CHB_[L] + ch;
    atomicMin((unsigned*)ws + O_CHMIN + g, __float_as_uint(mn));  // values >= 0
    atomicMax((unsigned*)ws + O_CHMAX + g, __float_as_uint(mx));
  }
}
__global__ void kA(P p) {
  int b = blockIdx.x;
  if      (b <  960) bodyA<0>(b,        p.in[0], p.ws);
  else if (b < 1472) bodyA<1>(b -  960, p.in[1], p.ws);
  else if (b < 1728) bodyA<2>(b - 1472, p.in[2], p.ws);
  else if (b < 2240) bodyA<3>(b - 1728, p.in[3], p.ws);
  else               bodyA<4>(b - 2240, p.in[4], p.ws);
}

// ---- kTB: per-channel thresholds + border fixup (subtract actual bins, add border-as-zero) ----
__global__ void kTB(P p) {
  int ch = blockIdx.x;
  float* ws = p.ws;
  int l = (ch < 64) ? 0 : (ch < 192) ? 1 : (ch < 448) ? 2 : (ch < 960) ? 3 : 4;
  int D = DIMS_[l];
  float mn = ws[O_CHMIN + ch], mx = ws[O_CHMAX + ch];
  float rng = mx - mn;
  // hb >= k  <=>  v >= mn + rng*k/6          (k = 1..5)
  // gb >= k  <=>  v >= mn + rng*(k+1)/1536   (k = 1..5)
  float th0, th1, th2, th3, th4, tg0, tg1, tg2, tg3, tg4;
  if (rng == 0.0f) {
    th0 = th1 = th2 = th3 = th4 = tg0 = tg1 = tg2 = tg3 = tg4 = INFINITY;
  } else {
    th0 = mn + rng * (1.0f / 6.0f); th1 = mn + rng * (2.0f / 6.0f);
    th2 = mn + rng * (3.0f / 6.0f); th3 = mn + rng * (4.0f / 6.0f);
    th4 = mn + rng * (5.0f / 6.0f);
    tg0 = mn + rng * (2.0f / 1536.0f); tg1 = mn + rng * (3.0f / 1536.0f);
    tg2 = mn + rng * (4.0f / 1536.0f); tg3 = mn + rng * (5.0f / 1536.0f);
    tg4 = mn + rng * (6.0f / 1536.0f);
  }
  int t = threadIdx.x;
  if (t == 0) {
    float* T = ws + O_CLUT + (size_t)ch * 16;
    T[0] = th0; T[1] = th1; T[2] = th2; T[3] = th3; T[4] = th4;
    T[5] = tg0; T[6] = tg1; T[7] = tg2; T[8] = tg3; T[9] = tg4;
  }
  // border pixels: count actual-value bins (to subtract from kB's full counts)
  const float* in = p.in[l] + (size_t)(ch - CHB_[l]) * D * D;
  int nb = 4 * D - 4;
  unsigned cH0 = 0, cH1 = 0, cH2 = 0, cH3 = 0, cH4 = 0;
  unsigned cG0 = 0, cG1 = 0, cG2 = 0, cG3 = 0, cG4 = 0, nval = 0;
  for (int j = t; j < nb; j += TPB) {
    int y, x;
    if (j < D)            { y = 0;               x = j;          }
    else if (j < 2 * D)   { y = D - 1;           x = j - D;      }
    else if (j < 3 * D - 2){ y = j - 2 * D + 1;  x = 0;          }
    else                  { y = j - (3 * D - 2) + 1; x = D - 1;  }
    float v = in[y * D + x];
    nval += __popcll(__ballot(1));
    cH0 += __popcll(__ballot(v >= th0)); cH1 += __popcll(__ballot(v >= th1));
    cH2 += __popcll(__ballot(v >= th2)); cH3 += __popcll(__ballot(v >= th3));
    cH4 += __popcll(__ballot(v >= th4));
    cG0 += __popcll(__ballot(v >= tg0)); cG1 += __popcll(__ballot(v >= tg1));
    cG2 += __popcll(__ballot(v >= tg2)); cG3 += __popcll(__ballot(v >= tg3));
    cG4 += __popcll(__ballot(v >= tg4));
  }
  unsigned* H = (unsigned*)ws + O_HIST + ch * 6;
  unsigned* G = (unsigned*)ws + O_GCNT + ch * 6;
  if ((t & 63) == 0) {
    atomicAdd(H + 0, (unsigned)(-(int)(nval - cH0)));
    atomicAdd(H + 1, (unsigned)(-(int)(cH0 - cH1)));
    atomicAdd(H + 2, (unsigned)(-(int)(cH1 - cH2)));
    atomicAdd(H + 3, (unsigned)(-(int)(cH2 - cH3)));
    atomicAdd(H + 4, (unsigned)(-(int)(cH3 - cH4)));
    atomicAdd(H + 5, (unsigned)(-(int)cH4));
    atomicAdd(G + 0, (unsigned)(-(int)(nval - cG0)));
    atomicAdd(G + 1, (unsigned)(-(int)(cG0 - cG1)));
    atomicAdd(G + 2, (unsigned)(-(int)(cG1 - cG2)));
    atomicAdd(G + 3, (unsigned)(-(int)(cG2 - cG3)));
    atomicAdd(G + 4, (unsigned)(-(int)(cG3 - cG4)));
    atomicAdd(G + 5, (unsigned)(-(int)cG4));
  }
  if (t == 0) {   // border-as-zero analytic counts
    int hb0 = (0.0f >= th0) + (0.0f >= th1) + (0.0f >= th2) + (0.0f >= th3) + (0.0f >= th4);
    int gb0 = (0.0f >= tg0) + (0.0f >= tg1) + (0.0f >= tg2) + (0.0f >= tg3) + (0.0f >= tg4);
    atomicAdd(H + hb0, (unsigned)nb);
    atomicAdd(G + gb0, (unsigned)nb);
  }
}

// ---------------- pass B: hist + gidx counts via ballots (no border logic) ----------------
template <int L>
__device__ void bodyB(int local, const float* __restrict__ in, float* ws) {
  constexpr int D = DIMS_[L], HW = D * D, HW4 = HW / 4;
  constexpr int BPC = (HW4 + 4095) / 4096;
  int ch = local / BPC, chunk = local % BPC;
  int g = CHB_[L] + ch;
  const float* T = ws + O_CLUT + (size_t)g * 16;
  float th0 = T[0], th1 = T[1], th2 = T[2], th3 = T[3], th4 = T[4];
  float tg0 = T[5], tg1 = T[6], tg2 = T[7], tg3 = T[8], tg4 = T[9];
  int nvec = HW4 - chunk * 4096; if (nvec > 4096) nvec = 4096;
  const float4* pv = (const float4*)(in + (size_t)ch * HW) + (size_t)chunk * 4096;
  int t = threadIdx.x;
  unsigned cH0 = 0, cH1 = 0, cH2 = 0, cH3 = 0, cH4 = 0;
  unsigned cG0 = 0, cG1 = 0, cG2 = 0, cG3 = 0, cG4 = 0, nv4 = 0;
  for (int i = 0; i < 16; i++) {
    int vi = i * TPB + t;
    if (vi < nvec) {
      float4 v = pv[vi];
      nv4 += __popcll(__ballot(1));
      float vv[4] = {v.x, v.y, v.z, v.w};
      #pragma unroll
      for (int j = 0; j < 4; j++) {
        float x = vv[j];
        cH0 += __popcll(__ballot(x >= th0)); cH1 += __popcll(__ballot(x >= th1));
        cH2 += __popcll(__ballot(x >= th2)); cH3 += __popcll(__ballot(x >= th3));
        cH4 += __popcll(__ballot(x >= th4));
        cG0 += __popcll(__ballot(x >= tg0)); cG1 += __popcll(__ballot(x >= tg1));
        cG2 += __popcll(__ballot(x >= tg2)); cG3 += __popcll(__ballot(x >= tg3));
        cG4 += __popcll(__ballot(x >= tg4));
      }
    }
  }
  if ((t & 63) == 0) {
    unsigned tot = nv4 * 4u;
    unsigned* H = (unsigned*)ws + O_HIST + g * 6;
    unsigned* G = (unsigned*)ws + O_GCNT + g * 6;
    atomicAdd(H + 0, tot - cH0); atomicAdd(H + 1, cH0 - cH1);
    atomicAdd(H + 2, cH1 - cH2); atomicAdd(H + 3, cH2 - cH3);
    atomicAdd(H + 4, cH3 - cH4); atomicAdd(H + 5, cH4);
    atomicAdd(G + 0, tot - cG0); atomicAdd(G + 1, cG0 - cG1);
    atomicAdd(G + 2, cG1 - cG2); atomicAdd(G + 3, cG2 - cG3);
    atomicAdd(G + 4, cG3 - cG4); atomicAdd(G + 5, cG4);
  }
}
__global__ void kB(P p) {
  int b = blockIdx.x;
  if      (b <  960) bodyB<0>(b,        p.in[0], p.ws);
  else if (b < 1472) bodyB<1>(b -  960, p.in[1], p.ws);
  else if (b < 1728) bodyB<2>(b - 1472, p.in[2], p.ws);
  else if (b < 2240) bodyB<3>(b - 1728, p.in[3], p.ws);
  else               bodyB<4>(b - 2240, p.in[4], p.ws);
}

// ---------------- kernel S: per-channel LUT construction ----------------
__global__ void kS(P p) {
  int ch = blockIdx.x * TPB + threadIdx.x;
  if (ch >= TOTCH) return;
  float* ws = p.ws;
  int l = (ch < 64) ? 0 : (ch < 192) ? 1 : (ch < 448) ? 2 : (ch < 960) ? 3 : 4;
  int D = DIMS_[l];
  int HW = D * D;
  int c0 = ch - CHB_[l];
  unsigned hc[6], gc[6];
  unsigned* H = (unsigned*)ws + O_HIST + ch * 6;
  unsigned* G = (unsigned*)ws + O_GCNT + ch * 6;
  #pragma unroll
  for (int k = 0; k < 6; k++) { hc[k] = H[k]; gc[k] = G[k]; }
  float HWf = (float)HW;
  float nh[6];
  #pragma unroll
  for (int k = 0; k < 6; k++) nh[k] = -logf((float)hc[k] / HWf + 1e-4f);
  float dmn = INFINITY, dmx = -INFINITY;
  #pragma unroll
  for (int k = 0; k < 6; k++) if (gc[k]) { dmn = fminf(dmn, nh[k]); dmx = fmaxf(dmx, nh[k]); }
  float dr = dmx - dmn;
  float dstn[6];
  #pragma unroll
  for (int k = 0; k < 6; k++) dstn[k] = (dr == 0.0f) ? 0.0f : ((nh[k] - dmn) / dr);
  float maxv = (dr == 0.0f) ? 0.0f : 1.0f;
  double s1 = 0.0;
  #pragma unroll
  for (int k = 0; k < 6; k++) s1 += (double)gc[k] * (double)dstn[k];
  float mean1 = (float)(s1 / (double)HW);
  float w1 = maxv - mean1; w1 *= w1;
  float lut1[6];
  #pragma unroll
  for (int k = 0; k < 6; k++) lut1[k] = dstn[k] * w1;
  // border-as-zero gidx bin (must match kTB)
  const float* T = ws + O_CLUT + (size_t)ch * 16;
  int gb = (0.0f >= T[5]) + (0.0f >= T[6]) + (0.0f >= T[7]) + (0.0f >= T[8]) + (0.0f >= T[9]);
  unsigned bcnt = (unsigned)(4 * D - 4);
  float lmn, lmx;
  double s2 = 0.0;
  if (c0 == 0) {   // channel 0 keeps its border
    lmn = INFINITY; lmx = -INFINITY;
    #pragma unroll
    for (int k = 0; k < 6; k++) if (gc[k]) {
      lmn = fminf(lmn, lut1[k]); lmx = fmaxf(lmx, lut1[k]);
      s2 += (double)gc[k] * (double)lut1[k];
    }
  } else {
    lmn = 0.0f; lmx = 0.0f;   // border zeros present
    #pragma unroll
    for (int k = 0; k < 6; k++) {
      unsigned ic = gc[k] - ((k == gb) ? bcnt : 0u);
      if (ic) {
        lmn = fminf(lmn, lut1[k]); lmx = fmaxf(lmx, lut1[k]);
        s2 += (double)ic * (double)lut1[k];
      }
    }
  }
  float mean2 = (float)(s2 / (double)HW);
  float w2 = lmx - mean2; w2 *= w2;
  float r2 = lmx - lmn;
  float lout[6];
  #pragma unroll
  for (int k = 0; k < 6; k++) lout[k] = (r2 == 0.0f) ? 0.0f : (((lut1[k] - lmn) / r2) * w2);
  float* LT = ws + O_CLUT + (size_t)ch * 16 + 10;
  #pragma unroll
  for (int k = 0; k < 6; k++) LT[k] = lout[k];
  float bc = (c0 == 0) ? lout[gb] : ((r2 == 0.0f) ? 0.0f : (((0.0f - lmn) / r2) * w2));
  atomicAdd(ws + O_BSUM + l, bc);
}

// ---- pass C: proc = sum_c LUT[gb_c(v)] ----
// 256 px per block (4 px/thread, float4); 4 waves split channels in contiguous
// quarters; LUT records staged in LDS (wave-uniform broadcast reads); border
// pixels get the precomputed BSUM constant at write time (no border logic in
// the hot loop); fused per-layer proc min/max.
template <int L>
__device__ void bodyC(int local, const float* __restrict__ in, float* ws,
                      float* slut, float* sred) {
  constexpr int D = DIMS_[L], HW = D * D, HW4 = HW / 4, C = CHS_[L];
  constexpr int Q = C / 4;
  int t = threadIdx.x, lane = t & 63, w = t >> 6;
  const float* gl = ws + O_CLUT + (size_t)CHB_[L] * 16;
  for (int i = t; i < C * 16; i += TPB) slut[i] = gl[i];
  __syncthreads();
  int p4 = local * 64 + lane;          // this lane's float4 index
  bool valid = p4 < HW4;
  float a0 = 0.0f, a1 = 0.0f, a2 = 0.0f, a3 = 0.0f;
  if (valid) {
    const float4* bp = (const float4*)in + p4 + (size_t)(w * Q) * HW4;
    const float* su = slut + (size_t)(w * Q) * 16;
    #pragma unroll 4
    for (int c = 0; c < Q; c++) {
      float4 v = bp[(size_t)c * HW4];
      const float* cl = su + c * 16 + 5;
      float g0 = cl[0], g1 = cl[1], g2 = cl[2], g3 = cl[3], g4 = cl[4];
      float l0 = cl[5], l1 = cl[6], l2 = cl[7], l3 = cl[8], l4 = cl[9], l5 = cl[10];
      float s;
      s = (v.x >= g0) ? l1 : l0; s = (v.x >= g1) ? l2 : s; s = (v.x >= g2) ? l3 : s;
      s = (v.x >= g3) ? l4 : s;  s = (v.x >= g4) ? l5 : s; a0 += s;
      s = (v.y >= g0) ? l1 : l0; s = (v.y >= g1) ? l2 : s; s = (v.y >= g2) ? l3 : s;
      s = (v.y >= g3) ? l4 : s;  s = (v.y >= g4) ? l5 : s; a1 += s;
      s = (v.z >= g0) ? l1 : l0; s = (v.z >= g1) ? l2 : s; s = (v.z >= g2) ? l3 : s;
      s = (v.z >= g3) ? l4 : s;  s = (v.z >= g4) ? l5 : s; a2 += s;
      s = (v.w >= g0) ? l1 : l0; s = (v.w >= g1) ? l2 : s; s = (v.w >= g2) ? l3 : s;
      s = (v.w >= g3) ? l4 : s;  s = (v.w >= g4) ? l5 : s; a3 += s;
    }
  }
  sred[0 * 256 + w * 64 + lane] = a0;
  sred[1 * 256 + w * 64 + lane] = a1;
  sred[2 * 256 + w * 64 + lane] = a2;
  sred[3 * 256 + w * 64 + lane] = a3;
  __syncthreads();
  if (w == 0) {
    float o[4];
    #pragma unroll
    for (int j = 0; j < 4; j++)
      o[j] = sred[j * 256 + lane] + sred[j * 256 + 64 + lane] +
             sred[j * 256 + 128 + lane] + sred[j * 256 + 192 + lane];
    float bs = ws[O_BSUM + L];
    int px0 = p4 * 4;
    #pragma unroll
    for (int j = 0; j < 4; j++) {
      int px = px0 + j, y = px / D, x = px - y * D;
      bool inr = ((unsigned)(x - 1) < (unsigned)(D - 2)) && ((unsigned)(y - 1) < (unsigned)(D - 2));
      if (!inr) o[j] = bs;
    }
    float mn, mx;
    if (valid) {
      float4* procL4 = (float4*)(ws + O_PROC + PROCB_[L]);
      procL4[p4] = make_float4(o[0], o[1], o[2], o[3]);
      mn = fminf(fminf(o[0], o[1]), fminf(o[2], o[3]));
      mx = fmaxf(fmaxf(o[0], o[1]), fmaxf(o[2], o[3]));
    } else { mn = INFINITY; mx = 0.0f; }
    for (int s = 32; s; s >>= 1) { mn = fminf(mn, __shfl_down(mn, s)); mx = fmaxf(mx, __shfl_down(mx, s)); }
    if (lane == 0) {
      atomicMin((unsigned*)ws + O_PMIN + L, __float_as_uint(mn));
      atomicMax((unsigned*)ws + O_PMAX + L, __float_as_uint(mx));
    }
  }
}
__global__ __launch_bounds__(TPB) void kC(P p) {
  __shared__ float slut[512 * 16];   // max C = 512 records of 16 floats
  __shared__ float sred[1024];
  int b = blockIdx.x;
  if      (b <  900) bodyC<0>(b,        p.in[0], p.ws, slut, sred);
  else if (b < 1125) bodyC<1>(b -  900, p.in[1], p.ws, slut, sred);
  else if (b < 1182) bodyC<2>(b - 1125, p.in[2], p.ws, slut, sred);
  else if (b < 1197) bodyC<3>(b - 1182, p.in[3], p.ws, slut, sred);
  else               bodyC<4>(b - 1197, p.in[4], p.ws, slut, sred);
}

// ---- pass F: normalize(proc,0,1) + threshold + jax bilinear resize, fused layer stats ----
template <int L>
__device__ float bodyF(int px, float* ws) {
  constexpr int D = DIMS_[L];
  constexpr float INV = (float)D / 240.0f;
  constexpr float KS = (INV > 1.0f) ? INV : 1.0f;
  int oy = px / 240, ox = px - oy * 240;
  float mnv = __uint_as_float(((unsigned*)ws)[O_PMIN + L]);
  float mxv = __uint_as_float(((unsigned*)ws)[O_PMAX + L]);
  float pr = mxv - mnv;
  const float* procL = ws + O_PROC + PROCB_[L];
  float sfy = ((float)oy + 0.5f) * INV - 0.5f;
  float sfx = ((float)ox + 0.5f) * INV - 0.5f;
  int y0 = (int)ceilf(sfy - KS);  if (y0 < 0) y0 = 0;
  int y1 = (int)floorf(sfy + KS); if (y1 > D - 1) y1 = D - 1;
  int x0 = (int)ceilf(sfx - KS);  if (x0 < 0) x0 = 0;
  int x1 = (int)floorf(sfx + KS); if (x1 > D - 1) x1 = D - 1;
  float wsx = 0.0f;
  for (int jx = x0; jx <= x1; jx++) wsx += fmaxf(1.0f - fabsf(sfx - (float)jx) / KS, 0.0f);
  float acc = 0.0f, wsy = 0.0f;
  for (int jy = y0; jy <= y1; jy++) {
    float wy = fmaxf(1.0f - fabsf(sfy - (float)jy) / KS, 0.0f);
    wsy += wy;
    if (wy > 0.0f) {
      const float* row = procL + jy * D;
      float rs = 0.0f;
      for (int jx = x0; jx <= x1; jx++) {
        float wx = fmaxf(1.0f - fabsf(sfx - (float)jx) / KS, 0.0f);
        if (wx > 0.0f) {
          float v = row[jx];
          float tv = (pr == 0.0f) ? 0.0f : ((v - mnv) / pr);
          tv = (tv < 0.2f) ? 0.0f : tv;
          rs += wx * tv;
        }
      }
      acc += wy * rs;
    }
  }
  return acc / (wsy * wsx);
}
__global__ void kF(P p) {
  float* ws = p.ws;
  int b = blockIdx.x, l = b / 225;
  int px = (b - l * 225) * TPB + threadIdx.x;
  float res;
  switch (l) {
    case 0: res = bodyF<0>(px, ws); break;
    case 1: res = bodyF<1>(px, ws); break;
    case 2: res = bodyF<2>(px, ws); break;
    case 3: res = bodyF<3>(px, ws); break;
    default: res = bodyF<4>(px, ws); break;
  }
  ws[O_RESZ + l * 57600 + px] = res;
  float mn = res, mx = res, s = res;
  for (int o = 32; o; o >>= 1) {
    mn = fminf(mn, __shfl_down(mn, o));
    mx = fmaxf(mx, __shfl_down(mx, o));
    s += __shfl_down(s, o);
  }
  __shared__ float smn[4], smx[4], ssm[4];
  int t = threadIdx.x, w = t >> 6;
  if ((t & 63) == 0) { smn[w] = mn; smx[w] = mx; ssm[w] = s; }
  __syncthreads();
  if (t == 0) {
    mn = fminf(fminf(smn[0], smn[1]), fminf(smn[2], smn[3]));
    mx = fmaxf(fmaxf(smx[0], smx[1]), fmaxf(smx[2], smx[3]));
    s = ssm[0] + ssm[1] + ssm[2] + ssm[3];
    atomicMin((unsigned*)ws + O_S3MIN + l, __float_as_uint(mn));
    atomicMax((unsigned*)ws + O_S3MAX + l, __float_as_uint(mx));
    atomicAdd(ws + O_S3SUM + l, s);
  }
}

// ---------------- G2: final ponder + normalize(.,0,256), groups + sum ----------------
__global__ void kG2(P p, float* __restrict__ out) {
  float* ws = p.ws;
  int px = blockIdx.x * TPB + threadIdx.x;   // 225*256 == 57600
  float sum = 0.0f;
  #pragma unroll
  for (int l = 0; l < 5; l++) {
    float v = ws[O_RESZ + l * 57600 + px];
    float mn3 = __uint_as_float(((unsigned*)ws)[O_S3MIN + l]);
    float mx3 = __uint_as_float(((unsigned*)ws)[O_S3MAX + l]);
    float mean3 = ws[O_S3SUM + l] / 57600.0f;
    float r3 = mx3 - mn3;
    float ov;
    if (r3 == 0.0f) ov = 0.0f;
    else {
      float w3 = mx3 - mean3; w3 *= w3;
      if (w3 == 0.0f) ov = 0.0f;
      else ov = ((v - mn3) / r3) * w3 / w3 * 256.0f;
    }
    out[57600 + px * 5 + l] = ov;
    sum += ov;
  }
  out[px] = sum;
}

extern "C" void kernel_launch(void* const* d_in, const int* in_sizes, int n_in,
                              void* d_out, int out_size, void* d_ws, size_t ws_size,
                              hipStream_t stream) {
  (void)in_sizes; (void)n_in; (void)out_size; (void)ws_size;
  P p;
  for (int i = 0; i < 5; i++) p.in[i] = (const float*)d_in[i];
  p.ws = (float*)d_ws;
  float* out = (float*)d_out;

  k_init<<<(O_PROC + TPB - 1) / TPB, TPB, 0, stream>>>(p.ws);
  kA  <<<2752, TPB, 0, stream>>>(p);
  kTB <<<1472, TPB, 0, stream>>>(p);
  kB  <<<2752, TPB, 0, stream>>>(p);
  kS  <<<6,    TPB, 0, stream>>>(p);
  kC  <<<1201, TPB, 0, stream>>>(p);
  kF  <<<1125, TPB, 0, stream>>>(p);
  kG2 <<<225,  TPB, 0, stream>>>(p, out);
}

// Round 4
// 293.998 us; speedup vs baseline: 1.5896x; 1.1541x over previous
//
#include <hip/hip_runtime.h>
#include <math.h>

#define TPB 256

// ---------------- layer geometry ----------------
constexpr int DIMS_[5]  = {480, 240, 120, 60, 30};
constexpr int CHS_ [5]  = {64, 128, 256, 512, 512};
constexpr int CHB_ [5]  = {0, 64, 192, 448, 960};
constexpr int TOTCH     = 1472;
constexpr int PROCB_[5] = {0, 230400, 288000, 302400, 306000};
constexpr int PROCTOT   = 306900;

// ---------------- ws layout (4-byte words) ----------------
constexpr int O_CHMIN = 0;                  // f32 [1472]
constexpr int O_CHMAX = 1472;               // f32 [1472]
constexpr int O_HIST  = 2944;               // u32 [1472*6]
constexpr int O_GCNT  = 11776;              // u32 [1472*6]
constexpr int O_CLUT  = 20608;              // f32 [1472*16]: unused[5], gthr[5], lut[6]
constexpr int O_BSUM  = O_CLUT + 16 * 1472; // 44160: f32 [5]
constexpr int O_PMIN  = O_BSUM + 5;         // u32 [5]
constexpr int O_PMAX  = O_PMIN + 5;         // u32 [5]
constexpr int O_S3MIN = O_PMAX + 5;         // u32 [5]
constexpr int O_S3MAX = O_S3MIN + 5;        // u32 [5]
constexpr int O_S3SUM = O_S3MAX + 5;        // f32 [5]
constexpr int O_PROC  = 44192;              // f32 [306900] (zero-init; chunked layers atomicAdd)
constexpr int O_RESZ  = O_PROC + PROCTOT;   // f32 [5*57600]
constexpr int N_INIT  = O_PROC + PROCTOT;   // init range

struct P {
  const float* in[5];
  float* ws;
};

// ---------------- threshold helpers (same formulas everywhere) ----------------
// hb >= k+1  <=>  v >= mn + rng*(k+1)/6       (k = 0..4)
// gb >= k+1  <=>  v >= mn + rng*(k+2)/1536    (k = 0..4)
__device__ __forceinline__ void mk_hthr(float mn, float rng, float* th) {
  if (rng == 0.0f) { th[0]=th[1]=th[2]=th[3]=th[4]=INFINITY; return; }
  th[0] = mn + rng * (1.0f / 6.0f); th[1] = mn + rng * (2.0f / 6.0f);
  th[2] = mn + rng * (3.0f / 6.0f); th[3] = mn + rng * (4.0f / 6.0f);
  th[4] = mn + rng * (5.0f / 6.0f);
}
__device__ __forceinline__ void mk_gthr(float mn, float rng, float* tg) {
  if (rng == 0.0f) { tg[0]=tg[1]=tg[2]=tg[3]=tg[4]=INFINITY; return; }
  tg[0] = mn + rng * (2.0f / 1536.0f); tg[1] = mn + rng * (3.0f / 1536.0f);
  tg[2] = mn + rng * (4.0f / 1536.0f); tg[3] = mn + rng * (5.0f / 1536.0f);
  tg[4] = mn + rng * (6.0f / 1536.0f);
}

// ---------------- init ----------------
__global__ void k_init(float* ws) {
  int i = blockIdx.x * TPB + threadIdx.x;
  if (i >= N_INIT) return;
  unsigned v = 0u;
  if (i < O_CHMAX) v = 0x7F800000u;                       // chmin = +inf
  else if (i >= O_PMIN  && i < O_PMAX)  v = 0x7F800000u;  // pmin
  else if (i >= O_S3MIN && i < O_S3MAX) v = 0x7F800000u;  // s3min
  ((unsigned*)ws)[i] = v;
}

// ---------------- pass A: per-channel min/max of border-zeroed map (float4) ----------------
template <int L>
__device__ void bodyA(int local, const float* __restrict__ in, float* ws) {
  constexpr int D = DIMS_[L], HW = D * D, HW4 = HW / 4;
  constexpr int BPC = (HW4 + 4095) / 4096;
  int ch = local / BPC, chunk = local % BPC;
  int nvec = HW4 - chunk * 4096; if (nvec > 4096) nvec = 4096;
  const float4* pv = (const float4*)(in + (size_t)ch * HW) + (size_t)chunk * 4096;
  int t = threadIdx.x;
  float mn = INFINITY, mx = 0.0f;
  for (int i = 0; i < 16; i++) {
    int vi = i * TPB + t;
    if (vi < nvec) {
      float4 v = pv[vi];
      float vv[4] = {v.x, v.y, v.z, v.w};
      int e0 = (chunk * 4096 + vi) * 4;
      #pragma unroll
      for (int j = 0; j < 4; j++) {
        int e = e0 + j, y = e / D, x = e - y * D;
        bool inr = ((unsigned)(x - 1) < (unsigned)(D - 2)) && ((unsigned)(y - 1) < (unsigned)(D - 2));
        float s = inr ? vv[j] : 0.0f;   // border-as-zero: exact map semantics
        mn = fminf(mn, s); mx = fmaxf(mx, s);
      }
    }
  }
  for (int o = 32; o; o >>= 1) { mn = fminf(mn, __shfl_down(mn, o)); mx = fmaxf(mx, __shfl_down(mx, o)); }
  __shared__ float smn[4], smx[4];
  int w = t >> 6;
  if ((t & 63) == 0) { smn[w] = mn; smx[w] = mx; }
  __syncthreads();
  if (t == 0) {
    mn = fminf(fminf(smn[0], smn[1]), fminf(smn[2], smn[3]));
    mx = fmaxf(fmaxf(smx[0], smx[1]), fmaxf(smx[2], smx[3]));
    int g = CHB_[L] + ch;
    atomicMin((unsigned*)ws + O_CHMIN + g, __float_as_uint(mn));  // values >= 0
    atomicMax((unsigned*)ws + O_CHMAX + g, __float_as_uint(mx));
  }
}
__global__ void kA(P p) {
  int b = blockIdx.x;
  if      (b <  960) bodyA<0>(b,        p.in[0], p.ws);
  else if (b < 1472) bodyA<1>(b -  960, p.in[1], p.ws);
  else if (b < 1728) bodyA<2>(b - 1472, p.in[2], p.ws);
  else if (b < 2240) bodyA<3>(b - 1728, p.in[3], p.ws);
  else               bodyA<4>(b - 2240, p.in[4], p.ws);
}

// ---- pass B: hist + gidx counts via ballots; thresholds inline; borders zeroed inline ----
template <int L>
__device__ void bodyB(int local, const float* __restrict__ in, float* ws) {
  constexpr int D = DIMS_[L], HW = D * D, HW4 = HW / 4;
  constexpr int BPC = (HW4 + 4095) / 4096;
  constexpr int DQ = D / 4;   // f4 per row (valid when D%4==0)
  int ch = local / BPC, chunk = local % BPC;
  int g = CHB_[L] + ch;
  float mn = ws[O_CHMIN + g], mx = ws[O_CHMAX + g], rng = mx - mn;
  float th[5], tg[5];
  mk_hthr(mn, rng, th);
  mk_gthr(mn, rng, tg);
  int nvec = HW4 - chunk * 4096; if (nvec > 4096) nvec = 4096;
  const float4* pv = (const float4*)(in + (size_t)ch * HW) + (size_t)chunk * 4096;
  int t = threadIdx.x;
  unsigned cH0 = 0, cH1 = 0, cH2 = 0, cH3 = 0, cH4 = 0;
  unsigned cG0 = 0, cG1 = 0, cG2 = 0, cG3 = 0, cG4 = 0, nv4 = 0;
  for (int i = 0; i < 16; i++) {
    int vi = i * TPB + t;
    if (vi < nvec) {
      float4 v = pv[vi];
      float vv[4] = {v.x, v.y, v.z, v.w};
      int f4i = chunk * 4096 + vi;
      if constexpr (D % 4 == 0) {       // whole f4 on one row
        int y = f4i / DQ, xq = f4i - y * DQ;
        if (y == 0 || y == D - 1) { vv[0] = vv[1] = vv[2] = vv[3] = 0.0f; }
        else {
          if (xq == 0)      vv[0] = 0.0f;
          if (xq == DQ - 1) vv[3] = 0.0f;
        }
      } else {                          // D==30: f4 may straddle rows
        int e0 = f4i * 4;
        #pragma unroll
        for (int j = 0; j < 4; j++) {
          int e = e0 + j, y = e / D, x = e - y * D;
          bool inr = ((unsigned)(x - 1) < (unsigned)(D - 2)) && ((unsigned)(y - 1) < (unsigned)(D - 2));
          if (!inr) vv[j] = 0.0f;
        }
      }
      nv4 += __popcll(__ballot(1));
      #pragma unroll
      for (int j = 0; j < 4; j++) {
        float x = vv[j];
        cH0 += __popcll(__ballot(x >= th[0])); cH1 += __popcll(__ballot(x >= th[1]));
        cH2 += __popcll(__ballot(x >= th[2])); cH3 += __popcll(__ballot(x >= th[3]));
        cH4 += __popcll(__ballot(x >= th[4]));
        cG0 += __popcll(__ballot(x >= tg[0])); cG1 += __popcll(__ballot(x >= tg[1]));
        cG2 += __popcll(__ballot(x >= tg[2])); cG3 += __popcll(__ballot(x >= tg[3]));
        cG4 += __popcll(__ballot(x >= tg[4]));
      }
    }
  }
  if ((t & 63) == 0) {
    unsigned tot = nv4 * 4u;
    unsigned* H = (unsigned*)ws + O_HIST + g * 6;
    unsigned* G = (unsigned*)ws + O_GCNT + g * 6;
    atomicAdd(H + 0, tot - cH0); atomicAdd(H + 1, cH0 - cH1);
    atomicAdd(H + 2, cH1 - cH2); atomicAdd(H + 3, cH2 - cH3);
    atomicAdd(H + 4, cH3 - cH4); atomicAdd(H + 5, cH4);
    atomicAdd(G + 0, tot - cG0); atomicAdd(G + 1, cG0 - cG1);
    atomicAdd(G + 2, cG1 - cG2); atomicAdd(G + 3, cG2 - cG3);
    atomicAdd(G + 4, cG3 - cG4); atomicAdd(G + 5, cG4);
  }
}
__global__ void kB(P p) {
  int b = blockIdx.x;
  if      (b <  960) bodyB<0>(b,        p.in[0], p.ws);
  else if (b < 1472) bodyB<1>(b -  960, p.in[1], p.ws);
  else if (b < 1728) bodyB<2>(b - 1472, p.in[2], p.ws);
  else if (b < 2240) bodyB<3>(b - 1728, p.in[3], p.ws);
  else               bodyB<4>(b - 2240, p.in[4], p.ws);
}

// ---------------- kernel S: per-channel LUT construction ----------------
__global__ void kS(P p) {
  int ch = blockIdx.x * TPB + threadIdx.x;
  if (ch >= TOTCH) return;
  float* ws = p.ws;
  int l = (ch < 64) ? 0 : (ch < 192) ? 1 : (ch < 448) ? 2 : (ch < 960) ? 3 : 4;
  int D = DIMS_[l];
  int HW = D * D;
  int c0 = ch - CHB_[l];
  unsigned hc[6], gc[6];
  unsigned* H = (unsigned*)ws + O_HIST + ch * 6;
  unsigned* G = (unsigned*)ws + O_GCNT + ch * 6;
  #pragma unroll
  for (int k = 0; k < 6; k++) { hc[k] = H[k]; gc[k] = G[k]; }
  float HWf = (float)HW;
  float nh[6];
  #pragma unroll
  for (int k = 0; k < 6; k++) nh[k] = -logf((float)hc[k] / HWf + 1e-4f);
  float dmn = INFINITY, dmx = -INFINITY;
  #pragma unroll
  for (int k = 0; k < 6; k++) if (gc[k]) { dmn = fminf(dmn, nh[k]); dmx = fmaxf(dmx, nh[k]); }
  float dr = dmx - dmn;
  float dstn[6];
  #pragma unroll
  for (int k = 0; k < 6; k++) dstn[k] = (dr == 0.0f) ? 0.0f : ((nh[k] - dmn) / dr);
  float maxv = (dr == 0.0f) ? 0.0f : 1.0f;
  double s1 = 0.0;
  #pragma unroll
  for (int k = 0; k < 6; k++) s1 += (double)gc[k] * (double)dstn[k];
  float mean1 = (float)(s1 / (double)HW);
  float w1 = maxv - mean1; w1 *= w1;
  float lut1[6];
  #pragma unroll
  for (int k = 0; k < 6; k++) lut1[k] = dstn[k] * w1;
  // gidx thresholds (inline) + border-as-zero gidx bin
  float mnc = ws[O_CHMIN + ch], mxc = ws[O_CHMAX + ch];
  float tg[5];
  mk_gthr(mnc, mxc - mnc, tg);
  int gb = (0.0f >= tg[0]) + (0.0f >= tg[1]) + (0.0f >= tg[2]) + (0.0f >= tg[3]) + (0.0f >= tg[4]);
  unsigned bcnt = (unsigned)(4 * D - 4);
  float lmn, lmx;
  double s2 = 0.0;
  if (c0 == 0) {   // channel 0 keeps its border
    lmn = INFINITY; lmx = -INFINITY;
    #pragma unroll
    for (int k = 0; k < 6; k++) if (gc[k]) {
      lmn = fminf(lmn, lut1[k]); lmx = fmaxf(lmx, lut1[k]);
      s2 += (double)gc[k] * (double)lut1[k];
    }
  } else {
    lmn = 0.0f; lmx = 0.0f;   // border zeros present
    #pragma unroll
    for (int k = 0; k < 6; k++) {
      unsigned ic = gc[k] - ((k == gb) ? bcnt : 0u);
      if (ic) {
        lmn = fminf(lmn, lut1[k]); lmx = fmaxf(lmx, lut1[k]);
        s2 += (double)ic * (double)lut1[k];
      }
    }
  }
  float mean2 = (float)(s2 / (double)HW);
  float w2 = lmx - mean2; w2 *= w2;
  float r2 = lmx - lmn;
  float lout[6];
  #pragma unroll
  for (int k = 0; k < 6; k++) lout[k] = (r2 == 0.0f) ? 0.0f : (((lut1[k] - lmn) / r2) * w2);
  float* T = ws + O_CLUT + (size_t)ch * 16;
  #pragma unroll
  for (int k = 0; k < 5; k++) T[5 + k] = tg[k];
  #pragma unroll
  for (int k = 0; k < 6; k++) T[10 + k] = lout[k];
  float bc = (c0 == 0) ? lout[gb] : ((r2 == 0.0f) ? 0.0f : (((0.0f - lmn) / r2) * w2));
  atomicAdd(ws + O_BSUM + l, bc);
}

// ---- pass C: proc = sum_c LUT[gb_c(v)] ----
// Uniform work units: (64-float4 tile) x (64-channel chunk) = 16k elements/block.
// 4 waves split the 64 channels (16 each). LUT records staged in LDS. Chunked
// layers accumulate via atomicAdd (proc zero-initialized); border pixels are
// written once by chunk 0 with BSUM. No min/max here (kD does it).
template <int L>
__device__ void bodyC(int local, const float* __restrict__ in, float* ws,
                      float* slut, float* sred) {
  constexpr int D = DIMS_[L], HW = D * D, HW4 = HW / 4, C = CHS_[L];
  constexpr int NT  = (HW4 + 63) / 64;   // tiles per layer
  constexpr int NCH = C / 64;            // channel chunks
  int tile = local % NT, chunk = local / NT;
  int cbase = CHB_[L] + chunk * 64;
  int t = threadIdx.x, lane = t & 63, w = t >> 6;
  const float* gl = ws + O_CLUT + (size_t)cbase * 16;
  for (int i = t; i < 1024; i += TPB) slut[i] = gl[i];
  __syncthreads();
  int p4 = tile * 64 + lane;
  bool valid = p4 < HW4;
  float a0 = 0.0f, a1 = 0.0f, a2 = 0.0f, a3 = 0.0f;
  if (valid) {
    const float4* bp = (const float4*)in + (size_t)(chunk * 64 + w * 16) * HW4 + p4;
    const float* su = slut + (w * 16) * 16;
    #pragma unroll 4
    for (int c = 0; c < 16; c++) {
      float4 v = bp[(size_t)c * HW4];
      const float* cl = su + c * 16 + 5;
      float g0 = cl[0], g1 = cl[1], g2 = cl[2], g3 = cl[3], g4 = cl[4];
      float l0 = cl[5], l1 = cl[6], l2 = cl[7], l3 = cl[8], l4 = cl[9], l5 = cl[10];
      float s;
      s = (v.x >= g0) ? l1 : l0; s = (v.x >= g1) ? l2 : s; s = (v.x >= g2) ? l3 : s;
      s = (v.x >= g3) ? l4 : s;  s = (v.x >= g4) ? l5 : s; a0 += s;
      s = (v.y >= g0) ? l1 : l0; s = (v.y >= g1) ? l2 : s; s = (v.y >= g2) ? l3 : s;
      s = (v.y >= g3) ? l4 : s;  s = (v.y >= g4) ? l5 : s; a1 += s;
      s = (v.z >= g0) ? l1 : l0; s = (v.z >= g1) ? l2 : s; s = (v.z >= g2) ? l3 : s;
      s = (v.z >= g3) ? l4 : s;  s = (v.z >= g4) ? l5 : s; a2 += s;
      s = (v.w >= g0) ? l1 : l0; s = (v.w >= g1) ? l2 : s; s = (v.w >= g2) ? l3 : s;
      s = (v.w >= g3) ? l4 : s;  s = (v.w >= g4) ? l5 : s; a3 += s;
    }
  }
  sred[0 * 256 + w * 64 + lane] = a0;
  sred[1 * 256 + w * 64 + lane] = a1;
  sred[2 * 256 + w * 64 + lane] = a2;
  sred[3 * 256 + w * 64 + lane] = a3;
  __syncthreads();
  if (w == 0 && valid) {
    float o[4];
    #pragma unroll
    for (int j = 0; j < 4; j++)
      o[j] = sred[j * 256 + lane] + sred[j * 256 + 64 + lane] +
             sred[j * 256 + 128 + lane] + sred[j * 256 + 192 + lane];
    float bs = ws[O_BSUM + L];
    float* procL = ws + O_PROC + PROCB_[L];
    int px0 = p4 * 4;
    if constexpr (NCH == 1) {
      #pragma unroll
      for (int j = 0; j < 4; j++) {
        int px = px0 + j, y = px / D, x = px - y * D;
        bool inr = ((unsigned)(x - 1) < (unsigned)(D - 2)) && ((unsigned)(y - 1) < (unsigned)(D - 2));
        if (!inr) o[j] = bs;
      }
      ((float4*)procL)[p4] = make_float4(o[0], o[1], o[2], o[3]);
    } else {
      #pragma unroll
      for (int j = 0; j < 4; j++) {
        int px = px0 + j, y = px / D, x = px - y * D;
        bool inr = ((unsigned)(x - 1) < (unsigned)(D - 2)) && ((unsigned)(y - 1) < (unsigned)(D - 2));
        if (inr) atomicAdd(procL + px, o[j]);
        else if (chunk == 0) procL[px] = bs;   // sole writer of border pixels
      }
    }
  }
}
__global__ __launch_bounds__(TPB) void kC(P p) {
  __shared__ float slut[1024];
  __shared__ float sred[1024];
  int b = blockIdx.x;
  if      (b <  900) bodyC<0>(b,        p.in[0], p.ws, slut, sred);
  else if (b < 1350) bodyC<1>(b -  900, p.in[1], p.ws, slut, sred);
  else if (b < 1578) bodyC<2>(b - 1350, p.in[2], p.ws, slut, sred);
  else if (b < 1698) bodyC<3>(b - 1578, p.in[3], p.ws, slut, sred);
  else               bodyC<4>(b - 1698, p.in[4], p.ws, slut, sred);
}

// ---------------- pass D: per-layer proc min/max ----------------
template <int L>
__device__ void bodyD(int chunk, float* ws) {
  constexpr int HW = DIMS_[L] * DIMS_[L];
  const float* pr = ws + O_PROC + PROCB_[L];
  int t = threadIdx.x;
  float mn = INFINITY, mx = 0.0f;   // proc >= 0
  #pragma unroll
  for (int i = 0; i < 16; i++) {
    int idx = chunk * 4096 + i * TPB + t;
    if (idx < HW) { float v = pr[idx]; mn = fminf(mn, v); mx = fmaxf(mx, v); }
  }
  for (int o = 32; o; o >>= 1) { mn = fminf(mn, __shfl_down(mn, o)); mx = fmaxf(mx, __shfl_down(mx, o)); }
  __shared__ float smn[4], smx[4];
  int w = t >> 6;
  if ((t & 63) == 0) { smn[w] = mn; smx[w] = mx; }
  __syncthreads();
  if (t == 0) {
    mn = fminf(fminf(smn[0], smn[1]), fminf(smn[2], smn[3]));
    mx = fmaxf(fmaxf(smx[0], smx[1]), fmaxf(smx[2], smx[3]));
    atomicMin((unsigned*)ws + O_PMIN + L, __float_as_uint(mn));
    atomicMax((unsigned*)ws + O_PMAX + L, __float_as_uint(mx));
  }
}
__global__ void kD(P p) {
  int b = blockIdx.x;
  if      (b < 57) bodyD<0>(b,      p.ws);
  else if (b < 72) bodyD<1>(b - 57, p.ws);
  else if (b < 76) bodyD<2>(b - 72, p.ws);
  else if (b < 77) bodyD<3>(b - 76, p.ws);
  else             bodyD<4>(b - 77, p.ws);
}

// ---- pass F: normalize(proc,0,1) + threshold + jax bilinear resize, fused layer stats ----
template <int L>
__device__ float bodyF(int px, float* ws) {
  constexpr int D = DIMS_[L];
  constexpr float INV = (float)D / 240.0f;
  constexpr float KS = (INV > 1.0f) ? INV : 1.0f;
  int oy = px / 240, ox = px - oy * 240;
  float mnv = __uint_as_float(((unsigned*)ws)[O_PMIN + L]);
  float mxv = __uint_as_float(((unsigned*)ws)[O_PMAX + L]);
  float pr = mxv - mnv;
  const float* procL = ws + O_PROC + PROCB_[L];
  float sfy = ((float)oy + 0.5f) * INV - 0.5f;
  float sfx = ((float)ox + 0.5f) * INV - 0.5f;
  int y0 = (int)ceilf(sfy - KS);  if (y0 < 0) y0 = 0;
  int y1 = (int)floorf(sfy + KS); if (y1 > D - 1) y1 = D - 1;
  int x0 = (int)ceilf(sfx - KS);  if (x0 < 0) x0 = 0;
  int x1 = (int)floorf(sfx + KS); if (x1 > D - 1) x1 = D - 1;
  float wsx = 0.0f;
  for (int jx = x0; jx <= x1; jx++) wsx += fmaxf(1.0f - fabsf(sfx - (float)jx) / KS, 0.0f);
  float acc = 0.0f, wsy = 0.0f;
  for (int jy = y0; jy <= y1; jy++) {
    float wy = fmaxf(1.0f - fabsf(sfy - (float)jy) / KS, 0.0f);
    wsy += wy;
    if (wy > 0.0f) {
      const float* row = procL + jy * D;
      float rs = 0.0f;
      for (int jx = x0; jx <= x1; jx++) {
        float wx = fmaxf(1.0f - fabsf(sfx - (float)jx) / KS, 0.0f);
        if (wx > 0.0f) {
          float v = row[jx];
          float tv = (pr == 0.0f) ? 0.0f : ((v - mnv) / pr);
          tv = (tv < 0.2f) ? 0.0f : tv;
          rs += wx * tv;
        }
      }
      acc += wy * rs;
    }
  }
  return acc / (wsy * wsx);
}
__global__ void kF(P p) {
  float* ws = p.ws;
  int b = blockIdx.x, l = b / 225;
  int px = (b - l * 225) * TPB + threadIdx.x;
  float res;
  switch (l) {
    case 0: res = bodyF<0>(px, ws); break;
    case 1: res = bodyF<1>(px, ws); break;
    case 2: res = bodyF<2>(px, ws); break;
    case 3: res = bodyF<3>(px, ws); break;
    default: res = bodyF<4>(px, ws); break;
  }
  ws[O_RESZ + l * 57600 + px] = res;
  float mn = res, mx = res, s = res;
  for (int o = 32; o; o >>= 1) {
    mn = fminf(mn, __shfl_down(mn, o));
    mx = fmaxf(mx, __shfl_down(mx, o));
    s += __shfl_down(s, o);
  }
  __shared__ float smn[4], smx[4], ssm[4];
  int t = threadIdx.x, w = t >> 6;
  if ((t & 63) == 0) { smn[w] = mn; smx[w] = mx; ssm[w] = s; }
  __syncthreads();
  if (t == 0) {
    mn = fminf(fminf(smn[0], smn[1]), fminf(smn[2], smn[3]));
    mx = fmaxf(fmaxf(smx[0], smx[1]), fmaxf(smx[2], smx[3]));
    s = ssm[0] + ssm[1] + ssm[2] + ssm[3];
    atomicMin((unsigned*)ws + O_S3MIN + l, __float_as_uint(mn));
    atomicMax((unsigned*)ws + O_S3MAX + l, __float_as_uint(mx));
    atomicAdd(ws + O_S3SUM + l, s);
  }
}

// ---------------- G2: final ponder + normalize(.,0,256), groups + sum ----------------
__global__ void kG2(P p, float* __restrict__ out) {
  float* ws = p.ws;
  int px = blockIdx.x * TPB + threadIdx.x;   // 225*256 == 57600
  float sum = 0.0f;
  #pragma unroll
  for (int l = 0; l < 5; l++) {
    float v = ws[O_RESZ + l * 57600 + px];
    float mn3 = __uint_as_float(((unsigned*)ws)[O_S3MIN + l]);
    float mx3 = __uint_as_float(((unsigned*)ws)[O_S3MAX + l]);
    float mean3 = ws[O_S3SUM + l] / 57600.0f;
    float r3 = mx3 - mn3;
    float ov;
    if (r3 == 0.0f) ov = 0.0f;
    else {
      float w3 = mx3 - mean3; w3 *= w3;
      if (w3 == 0.0f) ov = 0.0f;
      else ov = ((v - mn3) / r3) * w3 / w3 * 256.0f;
    }
    out[57600 + px * 5 + l] = ov;
    sum += ov;
  }
  out[px] = sum;
}

extern "C" void kernel_launch(void* const* d_in, const int* in_sizes, int n_in,
                              void* d_out, int out_size, void* d_ws, size_t ws_size,
                              hipStream_t stream) {
  (void)in_sizes; (void)n_in; (void)out_size; (void)ws_size;
  P p;
  for (int i = 0; i < 5; i++) p.in[i] = (const float*)d_in[i];
  p.ws = (float*)d_ws;
  float* out = (float*)d_out;

  k_init<<<(N_INIT + TPB - 1) / TPB, TPB, 0, stream>>>(p.ws);
  kA  <<<2752, TPB, 0, stream>>>(p);
  kB  <<<2752, TPB, 0, stream>>>(p);
  kS  <<<6,    TPB, 0, stream>>>(p);
  kC  <<<1730, TPB, 0, stream>>>(p);
  kD  <<<78,   TPB, 0, stream>>>(p);
  kF  <<<1125, TPB, 0, stream>>>(p);
  kG2 <<<225,  TPB, 0, stream>>>(p, out);
}